// Round 3
// baseline (659.170 us; speedup 1.0000x reference)
//
#include <hip/hip_runtime.h>
#include <cmath>

#define N_NODES 8192
#define HDIM 256
#define NFRAG 256
#define RMIX 0.3f
#define CSIM 0.8f
#define LN2 0.6931471805599453f
#define SMAX 96

// ---- workspace layout (bytes) ----
#define SI_OFF   ((size_t)0)                    // 8192*256*4  = 8 MB
#define VI_OFF   ((size_t)8388608)              // 24576*256*4 = 24 MB
#define T_OFF    ((size_t)33554432)             // 24576*256*4 = 24 MB
#define CNT_OFF  ((size_t)58720256)             // 256 ints
#define CUR_OFF  (CNT_OFF + 1024)               // 256 ints
#define OFF_OFF  (CNT_OFF + 2048)               // 256 ints
#define SORT_OFF (CNT_OFF + 3072)               // 8192 ints
#define ACC_OFF  (SORT_OFF + 32768)             // accum floats (32 B used)
#define FLG_OFF  (ACC_OFF + 128)                // int32 layout flag
#define NRM_OFF  (ACC_OFF + 256)                // slow-path norms (8192 floats)
#define FRGN_OFF (NRM_OFF + 32768)              // normalized int32 frag ids (8192)

// ============================= setup kernels =============================

__global__ void init_kernel(int* counts, int* cursor, float* acc, int* flag) {
    int t = threadIdx.x;
    if (t < NFRAG) { counts[t] = 0; cursor[t] = 0; }
    if (t < 8) acc[t] = 0.f;
    if (t == 0) *flag = 0;
}

// fragment_ids may arrive as raw int64 (reference dtype) or converted int32.
// int64 LE layout -> int32 view is [id,0,id,0,...]: all odd positions zero
// (ids < 256). Detect by OR-ing odd positions over the first 32 KB (valid in
// both layouts).
__global__ void detect_kernel(const int* __restrict__ buf, int* flag) {
    int i = blockIdx.x * 256 + threadIdx.x;       // 0..4095
    if (buf[2 * i + 1] != 0) atomicOr(flag, 1);   // 1 => plain int32 layout
}

__global__ void normalize_kernel(const int* __restrict__ buf, const int* __restrict__ flag,
                                 int* __restrict__ fragN) {
    int i = blockIdx.x * 256 + threadIdx.x;
    if (i < N_NODES) fragN[i] = (*flag) ? buf[i] : buf[2 * i];
}

__global__ void hist_kernel(const int* __restrict__ frag, int* counts) {
    int i = blockIdx.x * 256 + threadIdx.x;
    if (i < N_NODES) atomicAdd(&counts[frag[i]], 1);
}

__global__ void scan_kernel(const int* __restrict__ counts, int* offs) {
    __shared__ int tmp[NFRAG];
    int t = threadIdx.x;
    tmp[t] = counts[t];
    __syncthreads();
    for (int off = 1; off < NFRAG; off <<= 1) {
        int v = (t >= off) ? tmp[t - off] : 0;
        __syncthreads();
        tmp[t] += v;
        __syncthreads();
    }
    offs[t] = tmp[t] - counts[t];   // exclusive scan
}

__global__ void scatter_kernel(const int* __restrict__ frag, const int* __restrict__ offs,
                               int* cursor, int* sorted) {
    int i = blockIdx.x * 256 + threadIdx.x;
    if (i < N_NODES) {
        int f = frag[i];
        int pos = offs[f] + atomicAdd(&cursor[f], 1);
        sorted[pos] = i;
    }
}

// ============================= GEMM =============================
// Out[M,256] = act( mix(A0,A1) @ W + bias ), tile 128x128, BK=8, 256 thr,
// 8x8 micro-tile, software-pipelined global->register prefetch.

template<bool MIX, bool SSP_ACT, bool HAS_BIAS>
__global__ __launch_bounds__(256)
void gemm_fused(const float* __restrict__ A0, const float* __restrict__ A1,
                const float* __restrict__ W, const float* __restrict__ bias,
                float* __restrict__ Out)
{
    __shared__ __align__(16) float As[8][132];
    __shared__ __align__(16) float Bs[8][132];
    const int tid = threadIdx.x;
    const int tx = tid & 15;
    const int ty = tid >> 4;
    const int rowBase = blockIdx.x * 128;
    const int colBase = blockIdx.y * 128;
    const int lr = tid >> 1;            // 0..127
    const int lk = (tid & 1) << 2;      // 0 or 4
    const int bk = tid >> 5;            // 0..7
    const int bc = (tid & 31) << 2;     // 0..124

    float acc[8][8];
    #pragma unroll
    for (int i = 0; i < 8; ++i)
        #pragma unroll
        for (int j = 0; j < 8; ++j) acc[i][j] = 0.f;

    const float* arow0 = A0 + (size_t)(rowBase + lr) * HDIM;
    const float* arow1 = MIX ? (A1 + (size_t)(rowBase + lr) * HDIM) : A0;

    auto loadA = [&](int kb) -> float4 {
        if constexpr (MIX) {
            float4 s = *(const float4*)(arow0 + kb + lk);
            float4 l = *(const float4*)(arow1 + kb + lk);
            float4 r;
            r.x = s.x * RMIX + l.x * (1.f - RMIX);
            r.y = s.y * RMIX + l.y * (1.f - RMIX);
            r.z = s.z * RMIX + l.z * (1.f - RMIX);
            r.w = s.w * RMIX + l.w * (1.f - RMIX);
            return r;
        } else {
            return *(const float4*)(arow0 + kb + lk);
        }
    };
    auto loadB = [&](int kb) -> float4 {
        return *(const float4*)(W + (size_t)(kb + bk) * HDIM + colBase + bc);
    };

    float4 av = loadA(0);
    float4 bv = loadB(0);

    for (int kb = 0; kb < HDIM; kb += 8) {
        __syncthreads();                 // previous compute done reading LDS
        As[lk + 0][lr] = av.x;
        As[lk + 1][lr] = av.y;
        As[lk + 2][lr] = av.z;
        As[lk + 3][lr] = av.w;
        *(float4*)&Bs[bk][bc] = bv;
        __syncthreads();
        if (kb + 8 < HDIM) {             // prefetch next slab under compute
            av = loadA(kb + 8);
            bv = loadB(kb + 8);
        }
        #pragma unroll
        for (int k = 0; k < 8; ++k) {
            float4 a0 = *(const float4*)&As[k][ty << 2];
            float4 a1 = *(const float4*)&As[k][64 + (ty << 2)];
            float4 b0 = *(const float4*)&Bs[k][tx << 2];
            float4 b1 = *(const float4*)&Bs[k][64 + (tx << 2)];
            float ar[8] = {a0.x, a0.y, a0.z, a0.w, a1.x, a1.y, a1.z, a1.w};
            float br[8] = {b0.x, b0.y, b0.z, b0.w, b1.x, b1.y, b1.z, b1.w};
            #pragma unroll
            for (int i = 0; i < 8; ++i)
                #pragma unroll
                for (int j = 0; j < 8; ++j)
                    acc[i][j] += ar[i] * br[j];
        }
    }

    float bl[8] = {0, 0, 0, 0, 0, 0, 0, 0};
    if constexpr (HAS_BIAS) {
        float4 b0 = *(const float4*)(bias + colBase + (tx << 2));
        float4 b1 = *(const float4*)(bias + colBase + 64 + (tx << 2));
        bl[0] = b0.x; bl[1] = b0.y; bl[2] = b0.z; bl[3] = b0.w;
        bl[4] = b1.x; bl[5] = b1.y; bl[6] = b1.z; bl[7] = b1.w;
    }
    #pragma unroll
    for (int i = 0; i < 8; ++i) {
        int r = rowBase + ((i < 4) ? ((ty << 2) + i) : (64 + (ty << 2) + i - 4));
        float v[8];
        #pragma unroll
        for (int j = 0; j < 8; ++j) {
            float x = acc[i][j] + bl[j];
            if constexpr (SSP_ACT)
                x = fmaxf(x, 0.f) + log1pf(__expf(-fabsf(x))) - LN2;
            v[j] = x;
        }
        float4 lo = {v[0], v[1], v[2], v[3]};
        float4 hi = {v[4], v[5], v[6], v[7]};
        float* orow = Out + (size_t)r * HDIM + colBase;
        *(float4*)(orow + (tx << 2)) = lo;
        *(float4*)(orow + 64 + (tx << 2)) = hi;
    }
}

// ============================= fragment statistics =============================

__device__ __forceinline__ float blockReduceSum(float v, float* red) {
    #pragma unroll
    for (int off = 32; off > 0; off >>= 1)
        v += __shfl_down(v, off, 64);
    __syncthreads();
    if ((threadIdx.x & 63) == 0) red[threadIdx.x >> 6] = v;
    __syncthreads();
    return red[0] + red[1] + red[2] + red[3];
}

__device__ __forceinline__ float dot4(float4 a, float4 b) {
    return a.x * b.x + a.y * b.y + a.z * b.z + a.w * b.w;
}

// per-row inverse L2 norm -> invn[p]
__device__ void compute_invn(const float* __restrict__ Mat, int mult, int doff,
                             int c, int basep, const int* __restrict__ sorted,
                             float* invn, int tid)
{
    for (int p = tid; p < c; p += 256) {
        int nd = sorted[basep + p];
        const float4* row = (const float4*)(Mat + ((size_t)nd * mult + doff) * HDIM);
        float ss = 0.f;
        #pragma unroll 8
        for (int k = 0; k < 64; ++k) {
            float4 v = row[k];
            ss += v.x * v.x + v.y * v.y + v.z * v.z + v.w * v.w;
        }
        invn[p] = 1.0f / fmaxf(sqrtf(ss), 1e-12f);
    }
}

// fast path: Gram via 4x4 row-blocks x 4-way k-split, S staged in LDS
__device__ float pair_err_fast(const float* __restrict__ Mat, int mult, int doff,
                               int c, int basep, const int* __restrict__ sorted,
                               const float* invn, float* Ssh, int tid)
{
    int nb = (c + 3) >> 2, nb4 = nb << 2;
    int nbp = nb * (nb + 1) / 2;
    for (int i = tid; i < nb4 * nb4; i += 256) Ssh[i] = 0.f;
    __syncthreads();
    for (int u = tid; u < nbp * 4; u += 256) {
        int bp = u >> 2, kc = u & 3;
        int bi = 0, rem = bp;
        while (rem >= nb - bi) { rem -= nb - bi; ++bi; }
        int bj = bi + rem;
        int i0 = bi << 2, j0 = bj << 2;
        const float4* rA[4];
        const float4* rB[4];
        #pragma unroll
        for (int a = 0; a < 4; ++a) {
            int r = i0 + a;
            rA[a] = (r < c) ? (const float4*)(Mat + ((size_t)sorted[basep + r] * mult + doff) * HDIM) + kc * 16
                            : (const float4*)nullptr;
            r = j0 + a;
            rB[a] = (r < c) ? (const float4*)(Mat + ((size_t)sorted[basep + r] * mult + doff) * HDIM) + kc * 16
                            : (const float4*)nullptr;
        }
        float s[4][4] = {{0.f}};
        for (int k = 0; k < 16; ++k) {
            float4 av[4], bv[4];
            float4 z4 = {0.f, 0.f, 0.f, 0.f};
            #pragma unroll
            for (int a = 0; a < 4; ++a) av[a] = rA[a] ? rA[a][k] : z4;
            #pragma unroll
            for (int b = 0; b < 4; ++b) bv[b] = rB[b] ? rB[b][k] : z4;
            #pragma unroll
            for (int a = 0; a < 4; ++a)
                #pragma unroll
                for (int b = 0; b < 4; ++b)
                    s[a][b] += dot4(av[a], bv[b]);
        }
        #pragma unroll
        for (int a = 0; a < 4; ++a)
            #pragma unroll
            for (int b = 0; b < 4; ++b)
                atomicAdd(&Ssh[(i0 + a) * nb4 + (j0 + b)], s[a][b]);
    }
    __syncthreads();
    float e = 0.f;
    for (int pi = tid; pi < c * c; pi += 256) {
        int i = pi / c, j = pi - i * c;
        if (j > i) {
            float sv = Ssh[i * nb4 + j] * invn[i] * invn[j];
            float d = sv - CSIM;
            e += d * d;
        }
    }
    return e;
}

// slow path (c > SMAX; statistically ~never, kept for correctness)
__device__ float pair_err_slow(const float* __restrict__ Mat, int mult, int doff,
                               int c, int basep, const int* __restrict__ sorted,
                               const float* invn, int tid)
{
    float e = 0.f;
    for (long pi = tid; pi < (long)c * c; pi += 256) {
        int i = (int)(pi / c), j = (int)(pi - (long)i * c);
        if (j <= i) continue;
        const float4* ri = (const float4*)(Mat + ((size_t)sorted[basep + i] * mult + doff) * HDIM);
        const float4* rj = (const float4*)(Mat + ((size_t)sorted[basep + j] * mult + doff) * HDIM);
        float dt = 0.f;
        for (int k = 0; k < 64; ++k) dt += dot4(ri[k], rj[k]);
        float sv = dt * invn[i] * invn[j];
        float d = sv - CSIM;
        e += d * d;
    }
    return e;
}

__global__ __launch_bounds__(256)
void frag_kernel(const float* __restrict__ SI, const float* __restrict__ VI,
                 const int* __restrict__ counts, const int* __restrict__ offs,
                 const int* __restrict__ sorted, float* acc, float* nrm_global)
{
    int f = blockIdx.x, tid = threadIdx.x;
    int c = counts[f];
    if (c < 2) return;   // invalid fragment contributes nothing
    int basep = offs[f];

    __shared__ float red[4];
    __shared__ float invn_s[SMAX];
    __shared__ float Ssh[SMAX * SMAX];

    // ---- scalar mean / variance (thread owns dim tid) ----
    float mean = 0.f;
    for (int p = 0; p < c; ++p)
        mean += SI[(size_t)sorted[basep + p] * HDIM + tid];
    mean /= (float)c;
    float vh = 0.f;
    for (int p = 0; p < c; ++p) {
        float d = SI[(size_t)sorted[basep + p] * HDIM + tid] - mean;
        vh += d * d;
    }
    float s_var = blockReduceSum(vh, red);

    // ---- vector mean / variance (sum over 3 spatial dims) ----
    float vv = 0.f;
    for (int d = 0; d < 3; ++d) {
        float m = 0.f;
        for (int p = 0; p < c; ++p)
            m += VI[((size_t)sorted[basep + p] * 3 + d) * HDIM + tid];
        m /= (float)c;
        for (int p = 0; p < c; ++p) {
            float dd = VI[((size_t)sorted[basep + p] * 3 + d) * HDIM + tid] - m;
            vv += dd * dd;
        }
    }
    float v_var = blockReduceSum(vv, red);

    bool fast = (c <= SMAX);
    float* invn = fast ? invn_s : (nrm_global + basep);

    // ---- scalar pairwise similarity ----
    __syncthreads();
    compute_invn(SI, 1, 0, c, basep, sorted, invn, tid);
    __syncthreads();
    float se = fast ? pair_err_fast(SI, 1, 0, c, basep, sorted, invn, Ssh, tid)
                    : pair_err_slow(SI, 1, 0, c, basep, sorted, invn, tid);
    float s_sim = blockReduceSum(se, red);

    // ---- vector directional pairwise (3 dims) ----
    float dir_part = 0.f;
    for (int d = 0; d < 3; ++d) {
        __syncthreads();
        compute_invn(VI, 3, d, c, basep, sorted, invn, tid);
        __syncthreads();
        dir_part += fast ? pair_err_fast(VI, 3, d, c, basep, sorted, invn, Ssh, tid)
                         : pair_err_slow(VI, 3, d, c, basep, sorted, invn, tid);
    }
    float dir_err = blockReduceSum(dir_part, red);

    if (tid == 0) {
        float n = (float)c;
        float pc = 0.5f * n * (n - 1.f);
        float scalar_loss = s_var / n + s_sim / pc;
        float vector_loss = v_var / n + dir_err / (3.f * pc);
        float fl = 0.5f * scalar_loss + 0.5f * vector_loss;   // (1-VW)=VW=0.5
        atomicAdd(&acc[0], fl);
        atomicAdd(&acc[1], 1.0f);
    }
}

__global__ void finalize_kernel(const float* __restrict__ acc, float* __restrict__ out) {
    if (threadIdx.x == 0)
        out[0] = (acc[1] > 0.f) ? acc[0] / acc[1] : 0.f;
}

// ============================= launch =============================

extern "C" void kernel_launch(void* const* d_in, const int* in_sizes, int n_in,
                              void* d_out, int out_size, void* d_ws, size_t ws_size,
                              hipStream_t stream) {
    const float* s_short = (const float*)d_in[0];
    const float* s_long  = (const float*)d_in[1];
    const float* v_short = (const float*)d_in[2];
    const float* v_long  = (const float*)d_in[3];
    const float* W1 = (const float*)d_in[4];
    const float* b1 = (const float*)d_in[5];
    const float* W2 = (const float*)d_in[6];
    const float* b2 = (const float*)d_in[7];
    const float* V1 = (const float*)d_in[8];
    const float* V2 = (const float*)d_in[9];
    const int* fragRaw = (const int*)d_in[10];
    float* out = (float*)d_out;

    char* ws = (char*)d_ws;
    float* SI     = (float*)(ws + SI_OFF);
    float* VI     = (float*)(ws + VI_OFF);
    float* T      = (float*)(ws + T_OFF);
    int*   counts = (int*)(ws + CNT_OFF);
    int*   cursor = (int*)(ws + CUR_OFF);
    int*   offs   = (int*)(ws + OFF_OFF);
    int*   sorted = (int*)(ws + SORT_OFF);
    float* acc    = (float*)(ws + ACC_OFF);
    int*   flag   = (int*)(ws + FLG_OFF);
    float* nrm    = (float*)(ws + NRM_OFF);
    int*   fragN  = (int*)(ws + FRGN_OFF);

    init_kernel<<<1, 256, 0, stream>>>(counts, cursor, acc, flag);
    detect_kernel<<<16, 256, 0, stream>>>(fragRaw, flag);
    normalize_kernel<<<N_NODES / 256, 256, 0, stream>>>(fragRaw, flag, fragN);
    hist_kernel<<<N_NODES / 256, 256, 0, stream>>>(fragN, counts);
    scan_kernel<<<1, 256, 0, stream>>>(counts, offs);
    scatter_kernel<<<N_NODES / 256, 256, 0, stream>>>(fragN, offs, cursor, sorted);

    // scalar branch: T = ssp(mix@W1+b1); SI = T@W2+b2
    gemm_fused<true,  true,  true ><<<dim3(N_NODES / 128, 2), 256, 0, stream>>>(s_short, s_long, W1, b1, T);
    gemm_fused<false, false, true ><<<dim3(N_NODES / 128, 2), 256, 0, stream>>>(T, nullptr, W2, b2, SI);
    // vector branch (M = 3N): T = ssp(mix@V1); VI = T@V2
    gemm_fused<true,  true,  false><<<dim3(3 * N_NODES / 128, 2), 256, 0, stream>>>(v_short, v_long, V1, nullptr, T);
    gemm_fused<false, false, false><<<dim3(3 * N_NODES / 128, 2), 256, 0, stream>>>(T, nullptr, V2, nullptr, VI);

    frag_kernel<<<NFRAG, 256, 0, stream>>>(SI, VI, counts, offs, sorted, acc, nrm);
    finalize_kernel<<<1, 64, 0, stream>>>(acc, out);
}

// Round 5
// 319.732 us; speedup vs baseline: 2.0616x; 2.0616x over previous
//
#include <hip/hip_runtime.h>
#include <cmath>

#define N_NODES 8192
#define HDIM 256
#define NFRAG 256
#define RMIX 0.3f
#define CSIM 0.8f
#define LN2 0.6931471805599453f
#define CMAX 64          // LDS fast-path row capacity per (fragment, matrix)

// ---- workspace layout (bytes) ----
#define SI_OFF   ((size_t)0)                    // 8192*256*4  = 8 MB
#define VI_OFF   ((size_t)8388608)              // 24576*256*4 = 24 MB
#define T_OFF    ((size_t)33554432)             // 24576*256*4 = 24 MB
#define CNT_OFF  ((size_t)58720256)             // 256 ints
#define CUR_OFF  (CNT_OFF + 1024)               // 256 ints
#define OFF_OFF  (CNT_OFF + 2048)               // 256 ints
#define SORT_OFF (CNT_OFF + 3072)               // 8192 ints
#define ACC_OFF  (SORT_OFF + 32768)             // accum floats (32 B used)
#define FLG_OFF  (ACC_OFF + 128)                // int32 layout flag
#define NRM_OFF  (ACC_OFF + 256)                // slow-path norms: 4 regions x 8192 floats
#define FRGN_OFF (NRM_OFF + 4 * 32768)          // normalized int32 frag ids (8192)

// ============================= setup kernels =============================

__global__ void init_kernel(int* counts, int* cursor, float* acc, int* flag) {
    int t = threadIdx.x;
    if (t < NFRAG) { counts[t] = 0; cursor[t] = 0; }
    if (t < 8) acc[t] = 0.f;
    if (t == 0) *flag = 0;
}

// fragment_ids may arrive as raw int64 (reference dtype) or converted int32.
// int64 LE layout -> int32 view is [id,0,id,0,...]: all odd positions zero
// (ids < 256). Detect by OR-ing odd positions over the first 32 KB.
__global__ void detect_kernel(const int* __restrict__ buf, int* flag) {
    int i = blockIdx.x * 256 + threadIdx.x;       // 0..4095
    if (buf[2 * i + 1] != 0) atomicOr(flag, 1);   // 1 => plain int32 layout
}

__global__ void normalize_kernel(const int* __restrict__ buf, const int* __restrict__ flag,
                                 int* __restrict__ fragN) {
    int i = blockIdx.x * 256 + threadIdx.x;
    if (i < N_NODES) fragN[i] = (*flag) ? buf[i] : buf[2 * i];
}

__global__ void hist_kernel(const int* __restrict__ frag, int* counts) {
    int i = blockIdx.x * 256 + threadIdx.x;
    if (i < N_NODES) atomicAdd(&counts[frag[i]], 1);
}

__global__ void scan_kernel(const int* __restrict__ counts, int* offs) {
    __shared__ int tmp[NFRAG];
    int t = threadIdx.x;
    tmp[t] = counts[t];
    __syncthreads();
    for (int off = 1; off < NFRAG; off <<= 1) {
        int v = (t >= off) ? tmp[t - off] : 0;
        __syncthreads();
        tmp[t] += v;
        __syncthreads();
    }
    offs[t] = tmp[t] - counts[t];   // exclusive scan
}

__global__ void scatter_kernel(const int* __restrict__ frag, const int* __restrict__ offs,
                               int* cursor, int* sorted) {
    int i = blockIdx.x * 256 + threadIdx.x;
    if (i < N_NODES) {
        int f = frag[i];
        int pos = offs[f] + atomicAdd(&cursor[f], 1);
        sorted[pos] = i;
    }
}

// ============================= GEMM =============================
// Out[M,256] = act( mix(A0,A1) @ W + bias ). Tile BM=64 x BN=128, BK=8,
// 256 threads, 4x8 micro-tile, software-pipelined global prefetch.
// BM=64 (vs 128) doubles the grid: scalar GEMM fills all 256 CUs (was 128),
// and 32-reg accumulators allow multiple blocks/CU for barrier-latency hiding.

template<bool MIX, bool SSP_ACT, bool HAS_BIAS>
__global__ __launch_bounds__(256)
void gemm_fused(const float* __restrict__ A0, const float* __restrict__ A1,
                const float* __restrict__ W, const float* __restrict__ bias,
                float* __restrict__ Out)
{
    __shared__ __align__(16) float As[8][68];
    __shared__ __align__(16) float Bs[8][132];
    const int tid = threadIdx.x;
    const int tx = tid & 15;            // owns cols tx*4 and 64+tx*4
    const int ty = tid >> 4;            // owns rows ty*4 .. ty*4+3
    const int rowBase = blockIdx.x * 64;
    const int colBase = blockIdx.y * 128;
    const int lr = tid >> 1;            // 0..127 (A loader row, tid<128)
    const int lk = (tid & 1) << 2;      // 0 or 4
    const int bk = tid >> 5;            // 0..7
    const int bc = (tid & 31) << 2;     // 0..124

    float acc[4][8];
    #pragma unroll
    for (int i = 0; i < 4; ++i)
        #pragma unroll
        for (int j = 0; j < 8; ++j) acc[i][j] = 0.f;

    const bool loadsA = (tid < 128);    // wave-uniform (waves 0,1)
    const float* arow0 = A0 + (size_t)(rowBase + lr) * HDIM;
    const float* arow1 = MIX ? (A1 + (size_t)(rowBase + lr) * HDIM) : A0;

    auto loadA = [&](int kb) -> float4 {
        if constexpr (MIX) {
            float4 s = *(const float4*)(arow0 + kb + lk);
            float4 l = *(const float4*)(arow1 + kb + lk);
            float4 r;
            r.x = s.x * RMIX + l.x * (1.f - RMIX);
            r.y = s.y * RMIX + l.y * (1.f - RMIX);
            r.z = s.z * RMIX + l.z * (1.f - RMIX);
            r.w = s.w * RMIX + l.w * (1.f - RMIX);
            return r;
        } else {
            return *(const float4*)(arow0 + kb + lk);
        }
    };
    auto loadB = [&](int kb) -> float4 {
        return *(const float4*)(W + (size_t)(kb + bk) * HDIM + colBase + bc);
    };

    float4 av = {0.f, 0.f, 0.f, 0.f};
    if (loadsA) av = loadA(0);
    float4 bv = loadB(0);

    for (int kb = 0; kb < HDIM; kb += 8) {
        __syncthreads();                 // previous compute done reading LDS
        if (loadsA) {
            As[lk + 0][lr] = av.x;
            As[lk + 1][lr] = av.y;
            As[lk + 2][lr] = av.z;
            As[lk + 3][lr] = av.w;
        }
        *(float4*)&Bs[bk][bc] = bv;
        __syncthreads();
        if (kb + 8 < HDIM) {             // prefetch next slab under compute
            if (loadsA) av = loadA(kb + 8);
            bv = loadB(kb + 8);
        }
        #pragma unroll
        for (int k = 0; k < 8; ++k) {
            float4 a0 = *(const float4*)&As[k][ty << 2];
            float4 b0 = *(const float4*)&Bs[k][tx << 2];
            float4 b1 = *(const float4*)&Bs[k][64 + (tx << 2)];
            float ar[4] = {a0.x, a0.y, a0.z, a0.w};
            float br[8] = {b0.x, b0.y, b0.z, b0.w, b1.x, b1.y, b1.z, b1.w};
            #pragma unroll
            for (int i = 0; i < 4; ++i)
                #pragma unroll
                for (int j = 0; j < 8; ++j)
                    acc[i][j] += ar[i] * br[j];
        }
    }

    float bl[8] = {0, 0, 0, 0, 0, 0, 0, 0};
    if constexpr (HAS_BIAS) {
        float4 b0 = *(const float4*)(bias + colBase + (tx << 2));
        float4 b1 = *(const float4*)(bias + colBase + 64 + (tx << 2));
        bl[0] = b0.x; bl[1] = b0.y; bl[2] = b0.z; bl[3] = b0.w;
        bl[4] = b1.x; bl[5] = b1.y; bl[6] = b1.z; bl[7] = b1.w;
    }
    #pragma unroll
    for (int i = 0; i < 4; ++i) {
        int r = rowBase + (ty << 2) + i;
        float v[8];
        #pragma unroll
        for (int j = 0; j < 8; ++j) {
            float x = acc[i][j] + bl[j];
            if constexpr (SSP_ACT)
                x = fmaxf(x, 0.f) + log1pf(__expf(-fabsf(x))) - LN2;
            v[j] = x;
        }
        float4 lo = {v[0], v[1], v[2], v[3]};
        float4 hi = {v[4], v[5], v[6], v[7]};
        float* orow = Out + (size_t)r * HDIM + colBase;
        *(float4*)(orow + (tx << 2)) = lo;
        *(float4*)(orow + 64 + (tx << 2)) = hi;
    }
}

// ============================= fragment statistics =============================

__device__ __forceinline__ float blockReduceSum(float v, float* red) {
    #pragma unroll
    for (int off = 32; off > 0; off >>= 1)
        v += __shfl_down(v, off, 64);
    __syncthreads();
    if ((threadIdx.x & 63) == 0) red[threadIdx.x >> 6] = v;
    __syncthreads();
    return red[0] + red[1] + red[2] + red[3];
}

__device__ __forceinline__ float dot4(float4 a, float4 b) {
    return a.x * b.x + a.y * b.y + a.z * b.z + a.w * b.w;
}

// ---- slow-path helpers (c > CMAX; statistically absent, kept for correctness) ----

__device__ void compute_invn_g(const float* __restrict__ Mat, int mult, int doff,
                               int c, int basep, const int* __restrict__ sorted,
                               float* invn, int tid)
{
    for (int p = tid; p < c; p += 256) {
        int nd = sorted[basep + p];
        const float4* row = (const float4*)(Mat + ((size_t)nd * mult + doff) * HDIM);
        float ss = 0.f;
        #pragma unroll 8
        for (int k = 0; k < 64; ++k) {
            float4 v = row[k];
            ss += v.x * v.x + v.y * v.y + v.z * v.z + v.w * v.w;
        }
        invn[p] = 1.0f / fmaxf(sqrtf(ss), 1e-12f);
    }
}

__device__ float pair_err_slow(const float* __restrict__ Mat, int mult, int doff,
                               int c, int basep, const int* __restrict__ sorted,
                               const float* invn, int tid)
{
    float e = 0.f;
    for (long pi = tid; pi < (long)c * c; pi += 256) {
        int i = (int)(pi / c), j = (int)(pi - (long)i * c);
        if (j <= i) continue;
        const float4* ri = (const float4*)(Mat + ((size_t)sorted[basep + i] * mult + doff) * HDIM);
        const float4* rj = (const float4*)(Mat + ((size_t)sorted[basep + j] * mult + doff) * HDIM);
        float dt = 0.f;
        for (int k = 0; k < 64; ++k) dt += dot4(ri[k], rj[k]);
        float sv = dt * invn[i] * invn[j];
        float d = sv - CSIM;
        e += d * d;
    }
    return e;
}

// One block per (fragment f, matrix m): m=0 -> SI, m=1..3 -> VI dim m-1.
// Fast path stages the c x 256 matrix into LDS once (row stride 260 floats:
// 16B-aligned, rotates bank groups across rows), then computes mean/var
// (column-parallel), row norms, and 2x2-blocked Gram pair errors from LDS.
__global__ __launch_bounds__(256)
void fragmat_kernel(const float* __restrict__ SI, const float* __restrict__ VI,
                    const int* __restrict__ counts, const int* __restrict__ offs,
                    const int* __restrict__ sorted, float* acc, float* nrm_global)
{
    const int f = blockIdx.x, m = blockIdx.y, tid = threadIdx.x;
    const int c = counts[f];
    if (c < 2) return;                      // invalid fragment: no contribution
    const int basep = offs[f];
    const float* Mat = (m == 0) ? SI : VI;
    const int mult = (m == 0) ? 1 : 3;
    const int doff = (m == 0) ? 0 : (m - 1);

    __shared__ __align__(16) float Z[CMAX * 260];   // 65 KB (gfx950: 160 KB/CU)
    __shared__ float invn_s[CMAX];
    __shared__ float red[4];

    float var, err;

    if (c <= CMAX) {
        // ---- stage c x 256 into LDS (coalesced 1KB-per-row float4 loads) ----
        for (int u = tid; u < c * 64; u += 256) {
            int r = u >> 6, kc = u & 63;
            float4 v = *((const float4*)(Mat + ((size_t)sorted[basep + r] * mult + doff) * HDIM) + kc);
            *(float4*)&Z[r * 260 + (kc << 2)] = v;
        }
        __syncthreads();

        // ---- mean/var: thread tid owns column tid (2-way LDS aliasing = free) ----
        float msum = 0.f;
        for (int p = 0; p < c; ++p) msum += Z[p * 260 + tid];
        float mean = msum / (float)c;
        float vh = 0.f;
        for (int p = 0; p < c; ++p) {
            float d = Z[p * 260 + tid] - mean;
            vh += d * d;
        }
        var = blockReduceSum(vh, red);

        // ---- row inverse norms ----
        for (int p = tid; p < c; p += 256) {
            const float4* row = (const float4*)&Z[p * 260];
            float ss = 0.f;
            #pragma unroll 8
            for (int k = 0; k < 64; ++k) {
                float4 v = row[k];
                ss += v.x * v.x + v.y * v.y + v.z * v.z + v.w * v.w;
            }
            invn_s[p] = 1.0f / fmaxf(sqrtf(ss), 1e-12f);
        }
        __syncthreads();

        // ---- Gram pair errors, 2x2 register blocking over upper-tri blocks ----
        const int nb2 = (c + 1) >> 1;
        const int nbp = nb2 * (nb2 + 1) / 2;
        float e = 0.f;
        for (int u = tid; u < nbp; u += 256) {
            int bi = 0, rem = u;
            while (rem >= nb2 - bi) { rem -= nb2 - bi; ++bi; }
            int bj = bi + rem;
            int i0 = bi << 1, j0 = bj << 1;
            const float* zi0 = &Z[i0 * 260];
            const float* zi1 = &Z[(i0 + 1) * 260];
            const float* zj0 = &Z[j0 * 260];
            const float* zj1 = &Z[(j0 + 1) * 260];
            float s00 = 0.f, s01 = 0.f, s10 = 0.f, s11 = 0.f;
            #pragma unroll 4
            for (int k = 0; k < 64; ++k) {
                float4 a0 = *(const float4*)(zi0 + (k << 2));
                float4 a1 = *(const float4*)(zi1 + (k << 2));
                float4 b0 = *(const float4*)(zj0 + (k << 2));
                float4 b1 = *(const float4*)(zj1 + (k << 2));
                s00 += dot4(a0, b0);
                s01 += dot4(a0, b1);
                s10 += dot4(a1, b0);
                s11 += dot4(a1, b1);
            }
            // mask invalid pairs (j<=i or >=c); garbage rows never enter e
            int i1 = i0 + 1, j1 = j0 + 1;
            if (j0 > i0 && j0 < c) { float sv = s00 * invn_s[i0] * invn_s[j0] - CSIM; e += sv * sv; }
            if (j1 > i0 && j1 < c) { float sv = s01 * invn_s[i0] * invn_s[j1] - CSIM; e += sv * sv; }
            if (j0 > i1 && j0 < c) { float sv = s10 * invn_s[i1] * invn_s[j0] - CSIM; e += sv * sv; }
            if (j1 > i1 && j1 < c) { float sv = s11 * invn_s[i1] * invn_s[j1] - CSIM; e += sv * sv; }
        }
        err = blockReduceSum(e, red);
    } else {
        // ---- global-memory fallback ----
        float msum = 0.f;
        for (int p = 0; p < c; ++p)
            msum += Mat[((size_t)sorted[basep + p] * mult + doff) * HDIM + tid];
        float mean = msum / (float)c;
        float vh = 0.f;
        for (int p = 0; p < c; ++p) {
            float d = Mat[((size_t)sorted[basep + p] * mult + doff) * HDIM + tid] - mean;
            vh += d * d;
        }
        var = blockReduceSum(vh, red);

        float* invn = nrm_global + (size_t)m * N_NODES + basep;  // per-m region: no race
        compute_invn_g(Mat, mult, doff, c, basep, sorted, invn, tid);
        __syncthreads();
        float e = pair_err_slow(Mat, mult, doff, c, basep, sorted, invn, tid);
        err = blockReduceSum(e, red);
    }

    if (tid == 0) {
        float n = (float)c;
        float pc = 0.5f * n * (n - 1.f);
        // frag_loss = 0.5*(s_var/n + s_sim/pc) + 0.5*(v_var/n + dir_err/(3pc));
        // v_var and dir_err decompose as sums over the 3 VI dims.
        float w_err = (m == 0) ? (0.5f / pc) : (0.5f / (3.f * pc));
        float contrib = 0.5f * var / n + err * w_err;
        atomicAdd(&acc[0], contrib);
        if (m == 0) atomicAdd(&acc[1], 1.0f);   // valid-fragment count
    }
}

__global__ void finalize_kernel(const float* __restrict__ acc, float* __restrict__ out) {
    if (threadIdx.x == 0)
        out[0] = (acc[1] > 0.f) ? acc[0] / acc[1] : 0.f;
}

// ============================= launch =============================

extern "C" void kernel_launch(void* const* d_in, const int* in_sizes, int n_in,
                              void* d_out, int out_size, void* d_ws, size_t ws_size,
                              hipStream_t stream) {
    const float* s_short = (const float*)d_in[0];
    const float* s_long  = (const float*)d_in[1];
    const float* v_short = (const float*)d_in[2];
    const float* v_long  = (const float*)d_in[3];
    const float* W1 = (const float*)d_in[4];
    const float* b1 = (const float*)d_in[5];
    const float* W2 = (const float*)d_in[6];
    const float* b2 = (const float*)d_in[7];
    const float* V1 = (const float*)d_in[8];
    const float* V2 = (const float*)d_in[9];
    const int* fragRaw = (const int*)d_in[10];
    float* out = (float*)d_out;

    char* ws = (char*)d_ws;
    float* SI     = (float*)(ws + SI_OFF);
    float* VI     = (float*)(ws + VI_OFF);
    float* T      = (float*)(ws + T_OFF);
    int*   counts = (int*)(ws + CNT_OFF);
    int*   cursor = (int*)(ws + CUR_OFF);
    int*   offs   = (int*)(ws + OFF_OFF);
    int*   sorted = (int*)(ws + SORT_OFF);
    float* acc    = (float*)(ws + ACC_OFF);
    int*   flag   = (int*)(ws + FLG_OFF);
    float* nrm    = (float*)(ws + NRM_OFF);
    int*   fragN  = (int*)(ws + FRGN_OFF);

    init_kernel<<<1, 256, 0, stream>>>(counts, cursor, acc, flag);
    detect_kernel<<<16, 256, 0, stream>>>(fragRaw, flag);
    normalize_kernel<<<N_NODES / 256, 256, 0, stream>>>(fragRaw, flag, fragN);
    hist_kernel<<<N_NODES / 256, 256, 0, stream>>>(fragN, counts);
    scan_kernel<<<1, 256, 0, stream>>>(counts, offs);
    scatter_kernel<<<N_NODES / 256, 256, 0, stream>>>(fragN, offs, cursor, sorted);

    // scalar branch: T = ssp(mix@W1+b1); SI = T@W2+b2   (grid 256 blocks)
    gemm_fused<true,  true,  true ><<<dim3(N_NODES / 64, 2), 256, 0, stream>>>(s_short, s_long, W1, b1, T);
    gemm_fused<false, false, true ><<<dim3(N_NODES / 64, 2), 256, 0, stream>>>(T, nullptr, W2, b2, SI);
    // vector branch (M = 3N): T = ssp(mix@V1); VI = T@V2  (grid 768 blocks)
    gemm_fused<true,  true,  false><<<dim3(3 * N_NODES / 64, 2), 256, 0, stream>>>(v_short, v_long, V1, nullptr, T);
    gemm_fused<false, false, false><<<dim3(3 * N_NODES / 64, 2), 256, 0, stream>>>(T, nullptr, V2, nullptr, VI);

    fragmat_kernel<<<dim3(NFRAG, 4), 256, 0, stream>>>(SI, VI, counts, offs, sorted, acc, nrm);
    finalize_kernel<<<1, 64, 0, stream>>>(acc, out);
}

// Round 7
// 281.529 us; speedup vs baseline: 2.3414x; 1.1357x over previous
//
#include <hip/hip_runtime.h>
#include <cmath>

#define N_NODES 8192
#define HDIM 256
#define NFRAG 256
#define RMIX 0.3f
#define CSIM 0.8f
#define LN2 0.6931471805599453f
#define CMAX 64          // LDS fast-path row capacity per (fragment, matrix)

typedef __bf16 bf16x8 __attribute__((ext_vector_type(8)));
typedef float f32x4 __attribute__((ext_vector_type(4)));
typedef unsigned short us8 __attribute__((ext_vector_type(8)));
typedef unsigned short ushort_t;

// ---- workspace layout (bytes) ----
#define SI_OFF   ((size_t)0)                    // 8192*256*4  = 8 MB
#define VI_OFF   ((size_t)8388608)              // 24576*256*4 = 24 MB
#define THI_OFF  ((size_t)33554432)             // 24576*256*2 = 12,582,912
#define TLO_OFF  ((size_t)46137344)             // 12,582,912
#define WH_OFF   ((size_t)58720256)             // 4 * 65536 * 2 = 524,288
#define WL_OFF   ((size_t)59244544)             // 524,288
#define CNT_OFF  ((size_t)59768832)             // 256 ints
#define CUR_OFF  (CNT_OFF + 1024)
#define OFF_OFF  (CNT_OFF + 2048)
#define SORT_OFF (CNT_OFF + 3072)               // 8192 ints
#define ACC_OFF  (SORT_OFF + 32768)
#define FLG_OFF  (ACC_OFF + 128)
#define NRM_OFF  (ACC_OFF + 256)                // 4 regions x 8192 floats
#define FRGN_OFF (NRM_OFF + 4 * 32768)          // 8192 ints
// total ~59.97 MB

// ---- bf16 split helpers (RNE) ----
__device__ __forceinline__ ushort_t f2bf(float x) {
    unsigned u = __float_as_uint(x);
    return (ushort_t)((u + 0x7FFFu + ((u >> 16) & 1u)) >> 16);
}
__device__ __forceinline__ float bf2f(ushort_t h) {
    return __uint_as_float(((unsigned)h) << 16);
}
__device__ __forceinline__ f32x4 mfma_bf16(us8 a, us8 b, f32x4 c) {
    return __builtin_amdgcn_mfma_f32_16x16x32_bf16(
        __builtin_bit_cast(bf16x8, a), __builtin_bit_cast(bf16x8, b), c, 0, 0, 0);
}

// ============================= setup kernels =============================

__global__ void init_kernel(int* counts, int* cursor, float* acc, int* flag) {
    int t = threadIdx.x;
    if (t < NFRAG) { counts[t] = 0; cursor[t] = 0; }
    if (t < 8) acc[t] = 0.f;
    if (t == 0) *flag = 0;
}

// fragment_ids may arrive as raw int64 (reference dtype) or converted int32.
// int64 LE -> int32 view is [id,0,id,0,...]: odd positions all zero (ids<256).
__global__ void detect_kernel(const int* __restrict__ buf, int* flag) {
    int i = blockIdx.x * 256 + threadIdx.x;       // 0..4095
    if (buf[2 * i + 1] != 0) atomicOr(flag, 1);   // 1 => plain int32 layout
}

__global__ void normalize_kernel(const int* __restrict__ buf, const int* __restrict__ flag,
                                 int* __restrict__ fragN) {
    int i = blockIdx.x * 256 + threadIdx.x;
    if (i < N_NODES) fragN[i] = (*flag) ? buf[i] : buf[2 * i];
}

__global__ void hist_kernel(const int* __restrict__ frag, int* counts) {
    int i = blockIdx.x * 256 + threadIdx.x;
    if (i < N_NODES) atomicAdd(&counts[frag[i]], 1);
}

__global__ void scan_kernel(const int* __restrict__ counts, int* offs) {
    __shared__ int tmp[NFRAG];
    int t = threadIdx.x;
    tmp[t] = counts[t];
    __syncthreads();
    for (int off = 1; off < NFRAG; off <<= 1) {
        int v = (t >= off) ? tmp[t - off] : 0;
        __syncthreads();
        tmp[t] += v;
        __syncthreads();
    }
    offs[t] = tmp[t] - counts[t];   // exclusive scan
}

__global__ void scatter_kernel(const int* __restrict__ frag, const int* __restrict__ offs,
                               int* cursor, int* sorted) {
    int i = blockIdx.x * 256 + threadIdx.x;
    if (i < N_NODES) {
        int f = frag[i];
        int pos = offs[f] + atomicAdd(&cursor[f], 1);
        sorted[pos] = i;
    }
}

// Split the 4 weight matrices into bf16 hi/lo in MFMA-fragment-native layout:
// dst[((kb*256 + n)*4 + kg)*8 + e] = W[(kb*32 + kg*8 + e)*256 + n]
// so a lane (col n, k-group kg) reads 8 contiguous bf16 (16 B) per K32-step.
__global__ void wsplit_kernel(const float* __restrict__ W1, const float* __restrict__ W2,
                              const float* __restrict__ V1, const float* __restrict__ V2,
                              ushort_t* __restrict__ Whi, ushort_t* __restrict__ Wlo) {
    int m = blockIdx.y;
    const float* src = (m == 0) ? W1 : (m == 1) ? W2 : (m == 2) ? V1 : V2;
    ushort_t* dh = Whi + m * 65536;
    ushort_t* dl = Wlo + m * 65536;
    int o = blockIdx.x * 256 + threadIdx.x;   // 0..65535
    int e = o & 7, kg = (o >> 3) & 3, n = (o >> 5) & 255, kb = o >> 13;
    float x = src[(size_t)(kb * 32 + kg * 8 + e) * HDIM + n];
    ushort_t h = f2bf(x);
    dh[o] = h;
    dl[o] = f2bf(x - bf2f(h));
}

// ============================= MFMA GEMM =============================
// Out[M,256] = act( A @ W + bias ) with A = mix(A0,A1) (MIX) or split-bf16
// pair (Ahi,Alo). Split-bf16 4-pass (hihi+hilo+lohi+lolo) => ~fp32 accuracy.
// Block: 256 thr = 4 waves; tile BM=32 x BN=256 (full width): each wave owns
// 64 cols = 2x4 frags of 16x16x32. A is read/mixed/split exactly once.
// No LDS, no barriers: W fragments are L2-hot (256 KB/matrix pair).
// Fragment maps [m89/m91]: A row=lane&15, k=(lane>>4)*8+e (contiguous 8);
// D col=lane&15, row=(lane>>4)*4+reg.

template<bool MIX, bool SSP, bool BIAS, bool SPLIT>
__global__ __launch_bounds__(256)
void mfma_gemm(const void* __restrict__ A0v, const void* __restrict__ A1v,
               const ushort_t* __restrict__ Bhi, const ushort_t* __restrict__ Blo,
               const float* __restrict__ bias,
               float* __restrict__ OutF, ushort_t* __restrict__ OutHi,
               ushort_t* __restrict__ OutLo)
{
    const int tid = threadIdx.x;
    const int l   = tid & 63;
    const int wid = tid >> 6;
    const int lr  = l & 15;
    const int kg  = l >> 4;
    const int rowBase = blockIdx.x * 32;
    const int colW = wid * 64;          // wave's 64-column slice

    f32x4 acc[2][4];
    #pragma unroll
    for (int rf = 0; rf < 2; ++rf)
        #pragma unroll
        for (int cf = 0; cf < 4; ++cf)
            acc[rf][cf] = f32x4{0.f, 0.f, 0.f, 0.f};

    const ushort_t* bhp[4];
    const ushort_t* blp[4];
    #pragma unroll
    for (int cf = 0; cf < 4; ++cf) {
        int n = colW + cf * 16 + lr;
        bhp[cf] = Bhi + n * 32 + kg * 8;
        blp[cf] = Blo + n * 32 + kg * 8;
    }

    const float*    a0r[2];
    const float*    a1r[2];
    const ushort_t* ahr[2];
    const ushort_t* alr[2];
    #pragma unroll
    for (int rf = 0; rf < 2; ++rf) {
        size_t rowOff = (size_t)(rowBase + rf * 16 + lr) * HDIM;
        if constexpr (MIX) {
            a0r[rf] = (const float*)A0v + rowOff;
            a1r[rf] = (const float*)A1v + rowOff;
        } else {
            ahr[rf] = (const ushort_t*)A0v + rowOff;
            alr[rf] = (const ushort_t*)A1v + rowOff;
        }
    }

    for (int kb = 0; kb < 8; ++kb) {
        const int ko = kb * 32 + kg * 8;
        us8 ah[2], al[2];
        #pragma unroll
        for (int rf = 0; rf < 2; ++rf) {
            if constexpr (MIX) {
                float4 s0 = *(const float4*)(a0r[rf] + ko);
                float4 s1 = *(const float4*)(a0r[rf] + ko + 4);
                float4 t0 = *(const float4*)(a1r[rf] + ko);
                float4 t1 = *(const float4*)(a1r[rf] + ko + 4);
                float x[8];
                x[0] = s0.x * RMIX + t0.x * (1.f - RMIX);
                x[1] = s0.y * RMIX + t0.y * (1.f - RMIX);
                x[2] = s0.z * RMIX + t0.z * (1.f - RMIX);
                x[3] = s0.w * RMIX + t0.w * (1.f - RMIX);
                x[4] = s1.x * RMIX + t1.x * (1.f - RMIX);
                x[5] = s1.y * RMIX + t1.y * (1.f - RMIX);
                x[6] = s1.z * RMIX + t1.z * (1.f - RMIX);
                x[7] = s1.w * RMIX + t1.w * (1.f - RMIX);
                #pragma unroll
                for (int e = 0; e < 8; ++e) {
                    ushort_t h = f2bf(x[e]);
                    ah[rf][e] = h;
                    al[rf][e] = f2bf(x[e] - bf2f(h));
                }
            } else {
                ah[rf] = *(const us8*)(ahr[rf] + ko);
                al[rf] = *(const us8*)(alr[rf] + ko);
            }
        }
        #pragma unroll
        for (int cf = 0; cf < 4; ++cf) {
            us8 bh = *(const us8*)(bhp[cf] + kb * 8192);
            us8 bl = *(const us8*)(blp[cf] + kb * 8192);
            #pragma unroll
            for (int rf = 0; rf < 2; ++rf) {
                f32x4 t = acc[rf][cf];
                t = mfma_bf16(al[rf], bl, t);
                t = mfma_bf16(al[rf], bh, t);
                t = mfma_bf16(ah[rf], bl, t);
                t = mfma_bf16(ah[rf], bh, t);
                acc[rf][cf] = t;
            }
        }
    }

    // ---- epilogue: bias + optional SSP; write fp32 or split-bf16 ----
    #pragma unroll
    for (int rf = 0; rf < 2; ++rf) {
        #pragma unroll
        for (int cf = 0; cf < 4; ++cf) {
            int col = colW + cf * 16 + lr;
            float bv = 0.f;
            if constexpr (BIAS) bv = bias[col];
            #pragma unroll
            for (int r = 0; r < 4; ++r) {
                int row = rowBase + rf * 16 + kg * 4 + r;
                float x = acc[rf][cf][r] + bv;
                if constexpr (SSP)
                    x = fmaxf(x, 0.f) + log1pf(__expf(-fabsf(x))) - LN2;
                if constexpr (SPLIT) {
                    ushort_t h = f2bf(x);
                    OutHi[(size_t)row * HDIM + col] = h;
                    OutLo[(size_t)row * HDIM + col] = f2bf(x - bf2f(h));
                } else {
                    OutF[(size_t)row * HDIM + col] = x;
                }
            }
        }
    }
}

// ============================= fragment statistics =============================

__device__ __forceinline__ float blockReduceSum(float v, float* red) {
    #pragma unroll
    for (int off = 32; off > 0; off >>= 1)
        v += __shfl_down(v, off, 64);
    __syncthreads();
    if ((threadIdx.x & 63) == 0) red[threadIdx.x >> 6] = v;
    __syncthreads();
    return red[0] + red[1] + red[2] + red[3];
}

__device__ __forceinline__ float dot4(float4 a, float4 b) {
    return a.x * b.x + a.y * b.y + a.z * b.z + a.w * b.w;
}

__device__ void compute_invn_g(const float* __restrict__ Mat, int mult, int doff,
                               int c, int basep, const int* __restrict__ sorted,
                               float* invn, int tid)
{
    for (int p = tid; p < c; p += 256) {
        int nd = sorted[basep + p];
        const float4* row = (const float4*)(Mat + ((size_t)nd * mult + doff) * HDIM);
        float ss = 0.f;
        #pragma unroll 8
        for (int k = 0; k < 64; ++k) {
            float4 v = row[k];
            ss += v.x * v.x + v.y * v.y + v.z * v.z + v.w * v.w;
        }
        invn[p] = 1.0f / fmaxf(sqrtf(ss), 1e-12f);
    }
}

__device__ float pair_err_slow(const float* __restrict__ Mat, int mult, int doff,
                               int c, int basep, const int* __restrict__ sorted,
                               const float* invn, int tid)
{
    float e = 0.f;
    for (long pi = tid; pi < (long)c * c; pi += 256) {
        int i = (int)(pi / c), j = (int)(pi - (long)i * c);
        if (j <= i) continue;
        const float4* ri = (const float4*)(Mat + ((size_t)sorted[basep + i] * mult + doff) * HDIM);
        const float4* rj = (const float4*)(Mat + ((size_t)sorted[basep + j] * mult + doff) * HDIM);
        float dt = 0.f;
        for (int k = 0; k < 64; ++k) dt += dot4(ri[k], rj[k]);
        float sv = dt * invn[i] * invn[j];
        float d = sv - CSIM;
        e += d * d;
    }
    return e;
}

// One block per (fragment f, matrix m): m=0 -> SI, m=1..3 -> VI dim m-1.
__global__ __launch_bounds__(256)
void fragmat_kernel(const float* __restrict__ SI, const float* __restrict__ VI,
                    const int* __restrict__ counts, const int* __restrict__ offs,
                    const int* __restrict__ sorted, float* acc, float* nrm_global)
{
    const int f = blockIdx.x, m = blockIdx.y, tid = threadIdx.x;
    const int c = counts[f];
    if (c < 2) return;                      // invalid fragment: no contribution
    const int basep = offs[f];
    const float* Mat = (m == 0) ? SI : VI;
    const int mult = (m == 0) ? 1 : 3;
    const int doff = (m == 0) ? 0 : (m - 1);

    __shared__ __align__(16) float Z[CMAX * 260];   // 65 KB
    __shared__ float invn_s[CMAX];
    __shared__ float red[4];

    float var, err;

    if (c <= CMAX) {
        for (int u = tid; u < c * 64; u += 256) {
            int r = u >> 6, kc = u & 63;
            float4 v = *((const float4*)(Mat + ((size_t)sorted[basep + r] * mult + doff) * HDIM) + kc);
            *(float4*)&Z[r * 260 + (kc << 2)] = v;
        }
        __syncthreads();

        float msum = 0.f;
        for (int p = 0; p < c; ++p) msum += Z[p * 260 + tid];
        float mean = msum / (float)c;
        float vh = 0.f;
        for (int p = 0; p < c; ++p) {
            float d = Z[p * 260 + tid] - mean;
            vh += d * d;
        }
        var = blockReduceSum(vh, red);

        for (int p = tid; p < c; p += 256) {
            const float4* row = (const float4*)&Z[p * 260];
            float ss = 0.f;
            #pragma unroll 8
            for (int k = 0; k < 64; ++k) {
                float4 v = row[k];
                ss += v.x * v.x + v.y * v.y + v.z * v.z + v.w * v.w;
            }
            invn_s[p] = 1.0f / fmaxf(sqrtf(ss), 1e-12f);
        }
        __syncthreads();

        const int nb2 = (c + 1) >> 1;
        const int nbp = nb2 * (nb2 + 1) / 2;
        float e = 0.f;
        for (int u = tid; u < nbp; u += 256) {
            int bi = 0, rem = u;
            while (rem >= nb2 - bi) { rem -= nb2 - bi; ++bi; }
            int bj = bi + rem;
            int i0 = bi << 1, j0 = bj << 1;
            const float* zi0 = &Z[i0 * 260];
            const float* zi1 = &Z[(i0 + 1) * 260];
            const float* zj0 = &Z[j0 * 260];
            const float* zj1 = &Z[(j0 + 1) * 260];
            float s00 = 0.f, s01 = 0.f, s10 = 0.f, s11 = 0.f;
            #pragma unroll 4
            for (int k = 0; k < 64; ++k) {
                float4 a0 = *(const float4*)(zi0 + (k << 2));
                float4 a1 = *(const float4*)(zi1 + (k << 2));
                float4 b0 = *(const float4*)(zj0 + (k << 2));
                float4 b1 = *(const float4*)(zj1 + (k << 2));
                s00 += dot4(a0, b0);
                s01 += dot4(a0, b1);
                s10 += dot4(a1, b0);
                s11 += dot4(a1, b1);
            }
            int i1 = i0 + 1, j1 = j0 + 1;
            if (j0 > i0 && j0 < c) { float sv = s00 * invn_s[i0] * invn_s[j0] - CSIM; e += sv * sv; }
            if (j1 > i0 && j1 < c) { float sv = s01 * invn_s[i0] * invn_s[j1] - CSIM; e += sv * sv; }
            if (j0 > i1 && j0 < c) { float sv = s10 * invn_s[i1] * invn_s[j0] - CSIM; e += sv * sv; }
            if (j1 > i1 && j1 < c) { float sv = s11 * invn_s[i1] * invn_s[j1] - CSIM; e += sv * sv; }
        }
        err = blockReduceSum(e, red);
    } else {
        float msum = 0.f;
        for (int p = 0; p < c; ++p)
            msum += Mat[((size_t)sorted[basep + p] * mult + doff) * HDIM + tid];
        float mean = msum / (float)c;
        float vh = 0.f;
        for (int p = 0; p < c; ++p) {
            float d = Mat[((size_t)sorted[basep + p] * mult + doff) * HDIM + tid] - mean;
            vh += d * d;
        }
        var = blockReduceSum(vh, red);

        float* invn = nrm_global + (size_t)m * N_NODES + basep;
        compute_invn_g(Mat, mult, doff, c, basep, sorted, invn, tid);
        __syncthreads();
        float e = pair_err_slow(Mat, mult, doff, c, basep, sorted, invn, tid);
        err = blockReduceSum(e, red);
    }

    if (tid == 0) {
        float n = (float)c;
        float pc = 0.5f * n * (n - 1.f);
        float w_err = (m == 0) ? (0.5f / pc) : (0.5f / (3.f * pc));
        float contrib = 0.5f * var / n + err * w_err;
        atomicAdd(&acc[0], contrib);
        if (m == 0) atomicAdd(&acc[1], 1.0f);
    }
}

__global__ void finalize_kernel(const float* __restrict__ acc, float* __restrict__ out) {
    if (threadIdx.x == 0)
        out[0] = (acc[1] > 0.f) ? acc[0] / acc[1] : 0.f;
}

// ============================= launch =============================

extern "C" void kernel_launch(void* const* d_in, const int* in_sizes, int n_in,
                              void* d_out, int out_size, void* d_ws, size_t ws_size,
                              hipStream_t stream) {
    const float* s_short = (const float*)d_in[0];
    const float* s_long  = (const float*)d_in[1];
    const float* v_short = (const float*)d_in[2];
    const float* v_long  = (const float*)d_in[3];
    const float* W1 = (const float*)d_in[4];
    const float* b1 = (const float*)d_in[5];
    const float* W2 = (const float*)d_in[6];
    const float* b2 = (const float*)d_in[7];
    const float* V1 = (const float*)d_in[8];
    const float* V2 = (const float*)d_in[9];
    const int* fragRaw = (const int*)d_in[10];
    float* out = (float*)d_out;

    char* ws = (char*)d_ws;
    float*    SI     = (float*)(ws + SI_OFF);
    float*    VI     = (float*)(ws + VI_OFF);
    ushort_t* Thi    = (ushort_t*)(ws + THI_OFF);
    ushort_t* Tlo    = (ushort_t*)(ws + TLO_OFF);
    ushort_t* WH     = (ushort_t*)(ws + WH_OFF);
    ushort_t* WL     = (ushort_t*)(ws + WL_OFF);
    int*      counts = (int*)(ws + CNT_OFF);
    int*      cursor = (int*)(ws + CUR_OFF);
    int*      offs   = (int*)(ws + OFF_OFF);
    int*      sorted = (int*)(ws + SORT_OFF);
    float*    acc    = (float*)(ws + ACC_OFF);
    int*      flag   = (int*)(ws + FLG_OFF);
    float*    nrm    = (float*)(ws + NRM_OFF);
    int*      fragN  = (int*)(ws + FRGN_OFF);

    init_kernel<<<1, 256, 0, stream>>>(counts, cursor, acc, flag);
    detect_kernel<<<16, 256, 0, stream>>>(fragRaw, flag);
    normalize_kernel<<<N_NODES / 256, 256, 0, stream>>>(fragRaw, flag, fragN);
    hist_kernel<<<N_NODES / 256, 256, 0, stream>>>(fragN, counts);
    scan_kernel<<<1, 256, 0, stream>>>(counts, offs);
    scatter_kernel<<<N_NODES / 256, 256, 0, stream>>>(fragN, offs, cursor, sorted);
    wsplit_kernel<<<dim3(256, 4), 256, 0, stream>>>(W1, W2, V1, V2, WH, WL);

    // scalar branch: T = ssp(mix@W1+b1); SI = T@W2+b2
    mfma_gemm<true,  true,  true,  true ><<<dim3(N_NODES / 32), 256, 0, stream>>>(
        s_short, s_long, WH + 0 * 65536, WL + 0 * 65536, b1, nullptr, Thi, Tlo);
    mfma_gemm<false, false, true,  false><<<dim3(N_NODES / 32), 256, 0, stream>>>(
        Thi, Tlo, WH + 1 * 65536, WL + 1 * 65536, b2, SI, nullptr, nullptr);
    // vector branch (M = 3N): T = ssp(mix@V1); VI = T@V2
    mfma_gemm<true,  true,  false, true ><<<dim3(3 * N_NODES / 32), 256, 0, stream>>>(
        v_short, v_long, WH + 2 * 65536, WL + 2 * 65536, nullptr, nullptr, Thi, Tlo);
    mfma_gemm<false, false, false, false><<<dim3(3 * N_NODES / 32), 256, 0, stream>>>(
        Thi, Tlo, WH + 3 * 65536, WL + 3 * 65536, nullptr, VI, nullptr, nullptr);

    fragmat_kernel<<<dim3(NFRAG, 4), 256, 0, stream>>>(SI, VI, counts, offs, sorted, acc, nrm);
    finalize_kernel<<<1, 64, 0, stream>>>(acc, out);
}

// Round 9
// 255.120 us; speedup vs baseline: 2.5838x; 1.1035x over previous
//
#include <hip/hip_runtime.h>
#include <cmath>

#define N_NODES 8192
#define HDIM 256
#define NFRAG 256
#define RMIX 0.3f
#define CSIM 0.8f
#define LN2 0.6931471805599453f
#define CMAX 64          // LDS fast-path row capacity per (fragment, matrix)

typedef __bf16 bf16x8 __attribute__((ext_vector_type(8)));
typedef float f32x4 __attribute__((ext_vector_type(4)));
typedef unsigned short us8 __attribute__((ext_vector_type(8)));
typedef unsigned short us4 __attribute__((ext_vector_type(4)));
typedef unsigned short ushort_t;

// ---- workspace layout (bytes) ----
#define SI_OFF   ((size_t)0)                    // 8192*256*4  = 8 MB
#define VI_OFF   ((size_t)8388608)              // 24576*256*4 = 24 MB
#define WH_OFF   ((size_t)58720256)             // 4 * 65536 * 2 = 524,288
#define WL_OFF   ((size_t)59244544)             // 524,288
#define CNT_OFF  ((size_t)59768832)             // 256 ints
#define CUR_OFF  (CNT_OFF + 1024)
#define OFF_OFF  (CNT_OFF + 2048)
#define SORT_OFF (CNT_OFF + 3072)               // 8192 ints
#define ACC_OFF  (SORT_OFF + 32768)
#define FLG_OFF  (ACC_OFF + 128)
#define NRM_OFF  (ACC_OFF + 256)                // 4 regions x 8192 floats
#define FRGN_OFF (NRM_OFF + 4 * 32768)          // 8192 ints

// ---- bf16 split helpers (RNE) ----
__device__ __forceinline__ ushort_t f2bf(float x) {
    unsigned u = __float_as_uint(x);
    return (ushort_t)((u + 0x7FFFu + ((u >> 16) & 1u)) >> 16);
}
__device__ __forceinline__ float bf2f(ushort_t h) {
    return __uint_as_float(((unsigned)h) << 16);
}
__device__ __forceinline__ f32x4 mfma_bf16(us8 a, us8 b, f32x4 c) {
    return __builtin_amdgcn_mfma_f32_16x16x32_bf16(
        __builtin_bit_cast(bf16x8, a), __builtin_bit_cast(bf16x8, b), c, 0, 0, 0);
}

// ============================= setup kernels =============================

__global__ void init_kernel(int* counts, int* cursor, float* acc, int* flag) {
    int t = threadIdx.x;
    if (t < NFRAG) { counts[t] = 0; cursor[t] = 0; }
    if (t < 8) acc[t] = 0.f;
    if (t == 0) *flag = 0;
}

// fragment_ids may arrive as raw int64 (reference dtype) or converted int32.
// int64 LE -> int32 view is [id,0,id,0,...]: odd positions all zero (ids<256).
__global__ void detect_kernel(const int* __restrict__ buf, int* flag) {
    int i = blockIdx.x * 256 + threadIdx.x;       // 0..4095
    if (buf[2 * i + 1] != 0) atomicOr(flag, 1);   // 1 => plain int32 layout
}

__global__ void normalize_kernel(const int* __restrict__ buf, const int* __restrict__ flag,
                                 int* __restrict__ fragN) {
    int i = blockIdx.x * 256 + threadIdx.x;
    if (i < N_NODES) fragN[i] = (*flag) ? buf[i] : buf[2 * i];
}

__global__ void hist_kernel(const int* __restrict__ frag, int* counts) {
    int i = blockIdx.x * 256 + threadIdx.x;
    if (i < N_NODES) atomicAdd(&counts[frag[i]], 1);
}

__global__ void scan_kernel(const int* __restrict__ counts, int* offs) {
    __shared__ int tmp[NFRAG];
    int t = threadIdx.x;
    tmp[t] = counts[t];
    __syncthreads();
    for (int off = 1; off < NFRAG; off <<= 1) {
        int v = (t >= off) ? tmp[t - off] : 0;
        __syncthreads();
        tmp[t] += v;
        __syncthreads();
    }
    offs[t] = tmp[t] - counts[t];   // exclusive scan
}

__global__ void scatter_kernel(const int* __restrict__ frag, const int* __restrict__ offs,
                               int* cursor, int* sorted) {
    int i = blockIdx.x * 256 + threadIdx.x;
    if (i < N_NODES) {
        int f = frag[i];
        int pos = offs[f] + atomicAdd(&cursor[f], 1);
        sorted[pos] = i;
    }
}

// Split the 4 weight matrices into bf16 hi/lo in MFMA-fragment-native layout:
// dst[((kb*256 + n)*4 + kg)*8 + e] = W[(kb*32 + kg*8 + e)*256 + n]
__global__ void wsplit_kernel(const float* __restrict__ W1, const float* __restrict__ W2,
                              const float* __restrict__ V1, const float* __restrict__ V2,
                              ushort_t* __restrict__ Whi, ushort_t* __restrict__ Wlo) {
    int m = blockIdx.y;
    const float* src = (m == 0) ? W1 : (m == 1) ? W2 : (m == 2) ? V1 : V2;
    ushort_t* dh = Whi + m * 65536;
    ushort_t* dl = Wlo + m * 65536;
    int o = blockIdx.x * 256 + threadIdx.x;   // 0..65535
    int e = o & 7, kg = (o >> 3) & 3, n = (o >> 5) & 255, kb = o >> 13;
    float x = src[(size_t)(kb * 32 + kg * 8 + e) * HDIM + n];
    ushort_t h = f2bf(x);
    dh[o] = h;
    dl[o] = f2bf(x - bf2f(h));
}

// ============================= fused 2-layer MLP (MFMA) =============================
// Out[M,256] = mix(A0,A1) -> @W1 (+b1) -> ssp -> @W2 (+b2), split-bf16 4-pass.
// Block = 256 thr (4 waves), BM=32 rows, BN=256 (full width => layer-2 local).
// LDS 32 KB holds the 32x256 activation tile as bf16 hi/lo, XOR-swizzled
// (elem idx ^= (row&7)<<3 -> byte ^ (row&7)<<4), reused for A then T.
// SWAPPED mfma operands: D = mfma(W_frag, X_frag): lane holds output row m=lr
// and 4 CONSECUTIVE cols n=kg*4+r -> b64 LDS writes / float4 global stores.
// Maps verified on HW (round-7 absmax 0.0): A-pos row=lane&15,k=(lane>>4)*8+e;
// B-pos col=lane&15,k likewise; D col=lane&15,row=(lane>>4)*4+reg.

template<bool BIAS1, bool BIAS2>
__global__ __launch_bounds__(256)
void mlp_fused(const float* __restrict__ A0, const float* __restrict__ A1,
               const ushort_t* __restrict__ B1h, const ushort_t* __restrict__ B1l,
               const ushort_t* __restrict__ B2h, const ushort_t* __restrict__ B2l,
               const float* __restrict__ b1, const float* __restrict__ b2,
               float* __restrict__ Out)
{
    __shared__ ushort_t Zh[32 * 256];   // 16 KB
    __shared__ ushort_t Zl[32 * 256];   // 16 KB

    const int tid = threadIdx.x;
    const int l   = tid & 63;
    const int wid = tid >> 6;
    const int lr  = l & 15;
    const int kg  = l >> 4;
    const int rowBase = blockIdx.x * 32;
    const int colW = wid * 64;

    // ---- phase 0: coalesced load + mix + split -> LDS ----
    {
        int r  = tid >> 3;               // 0..31 local row
        int c0 = (tid & 7) * 32;         // 32-float run
        const float* ps = A0 + (size_t)(rowBase + r) * HDIM + c0;
        const float* pl = A1 + (size_t)(rowBase + r) * HDIM + c0;
        int swz = (r & 7) << 3;
        #pragma unroll
        for (int cc = 0; cc < 4; ++cc) {
            float4 s0 = *(const float4*)(ps + cc * 8);
            float4 s1 = *(const float4*)(ps + cc * 8 + 4);
            float4 t0 = *(const float4*)(pl + cc * 8);
            float4 t1 = *(const float4*)(pl + cc * 8 + 4);
            float x[8];
            x[0] = s0.x * RMIX + t0.x * (1.f - RMIX);
            x[1] = s0.y * RMIX + t0.y * (1.f - RMIX);
            x[2] = s0.z * RMIX + t0.z * (1.f - RMIX);
            x[3] = s0.w * RMIX + t0.w * (1.f - RMIX);
            x[4] = s1.x * RMIX + t1.x * (1.f - RMIX);
            x[5] = s1.y * RMIX + t1.y * (1.f - RMIX);
            x[6] = s1.z * RMIX + t1.z * (1.f - RMIX);
            x[7] = s1.w * RMIX + t1.w * (1.f - RMIX);
            us8 h, lo;
            #pragma unroll
            for (int e = 0; e < 8; ++e) {
                ushort_t hh = f2bf(x[e]);
                h[e] = hh;
                lo[e] = f2bf(x[e] - bf2f(hh));
            }
            int idx = r * 256 + ((c0 + cc * 8) ^ swz);
            *(us8*)&Zh[idx] = h;
            *(us8*)&Zl[idx] = lo;
        }
    }
    __syncthreads();

    // ---- W fragment pointers (lane-level): n = colW + nf*16 + lr ----
    const ushort_t *w1h[4], *w1l[4], *w2h[4], *w2l[4];
    #pragma unroll
    for (int nf = 0; nf < 4; ++nf) {
        int n = colW + nf * 16 + lr;
        int off = n * 32 + kg * 8;
        w1h[nf] = B1h + off;  w1l[nf] = B1l + off;
        w2h[nf] = B2h + off;  w2l[nf] = B2l + off;
    }

    // ---- phase 1: acc = mix @ W1 ----
    f32x4 acc[2][4];
    #pragma unroll
    for (int mf = 0; mf < 2; ++mf)
        #pragma unroll
        for (int nf = 0; nf < 4; ++nf)
            acc[mf][nf] = f32x4{0.f, 0.f, 0.f, 0.f};

    for (int kb = 0; kb < 8; ++kb) {
        const int kx = kb * 32 + kg * 8;
        us8 ah[2], al[2];
        #pragma unroll
        for (int mf = 0; mf < 2; ++mf) {
            int m = mf * 16 + lr;
            int idx = m * 256 + (kx ^ ((m & 7) << 3));
            ah[mf] = *(const us8*)&Zh[idx];
            al[mf] = *(const us8*)&Zl[idx];
        }
        #pragma unroll
        for (int nf = 0; nf < 4; ++nf) {
            us8 wh = *(const us8*)(w1h[nf] + kb * 8192);
            us8 wl = *(const us8*)(w1l[nf] + kb * 8192);
            #pragma unroll
            for (int mf = 0; mf < 2; ++mf) {
                f32x4 t = acc[mf][nf];
                t = mfma_bf16(wl, al[mf], t);
                t = mfma_bf16(wl, ah[mf], t);
                t = mfma_bf16(wh, al[mf], t);
                t = mfma_bf16(wh, ah[mf], t);
                acc[mf][nf] = t;
            }
        }
    }
    __syncthreads();   // all waves done reading A tile

    // ---- layer-1 epilogue: bias + SSP, split, T -> LDS (overwrites A) ----
    #pragma unroll
    for (int mf = 0; mf < 2; ++mf) {
        int m = mf * 16 + lr;
        #pragma unroll
        for (int nf = 0; nf < 4; ++nf) {
            int n0 = colW + nf * 16 + kg * 4;
            float4 bb = {0.f, 0.f, 0.f, 0.f};
            if constexpr (BIAS1) bb = *(const float4*)(b1 + n0);
            us4 h4, l4;
            #pragma unroll
            for (int r = 0; r < 4; ++r) {
                float x = acc[mf][nf][r] + ((const float*)&bb)[r];
                x = fmaxf(x, 0.f) + log1pf(__expf(-fabsf(x))) - LN2;   // ssp
                ushort_t hh = f2bf(x);
                h4[r] = hh;
                l4[r] = f2bf(x - bf2f(hh));
            }
            int idx = m * 256 + (n0 ^ ((m & 7) << 3));
            *(us4*)&Zh[idx] = h4;
            *(us4*)&Zl[idx] = l4;
        }
    }
    __syncthreads();

    // ---- phase 2: acc2 = T @ W2 ----
    f32x4 acc2[2][4];
    #pragma unroll
    for (int mf = 0; mf < 2; ++mf)
        #pragma unroll
        for (int nf = 0; nf < 4; ++nf)
            acc2[mf][nf] = f32x4{0.f, 0.f, 0.f, 0.f};

    for (int kb = 0; kb < 8; ++kb) {
        const int kx = kb * 32 + kg * 8;
        us8 ah[2], al[2];
        #pragma unroll
        for (int mf = 0; mf < 2; ++mf) {
            int m = mf * 16 + lr;
            int idx = m * 256 + (kx ^ ((m & 7) << 3));
            ah[mf] = *(const us8*)&Zh[idx];
            al[mf] = *(const us8*)&Zl[idx];
        }
        #pragma unroll
        for (int nf = 0; nf < 4; ++nf) {
            us8 wh = *(const us8*)(w2h[nf] + kb * 8192);
            us8 wl = *(const us8*)(w2l[nf] + kb * 8192);
            #pragma unroll
            for (int mf = 0; mf < 2; ++mf) {
                f32x4 t = acc2[mf][nf];
                t = mfma_bf16(wl, al[mf], t);
                t = mfma_bf16(wl, ah[mf], t);
                t = mfma_bf16(wh, al[mf], t);
                t = mfma_bf16(wh, ah[mf], t);
                acc2[mf][nf] = t;
            }
        }
    }

    // ---- final epilogue: bias2, float4 store ----
    #pragma unroll
    for (int mf = 0; mf < 2; ++mf) {
        int row = rowBase + mf * 16 + lr;
        #pragma unroll
        for (int nf = 0; nf < 4; ++nf) {
            int n0 = colW + nf * 16 + kg * 4;
            float4 bb = {0.f, 0.f, 0.f, 0.f};
            if constexpr (BIAS2) bb = *(const float4*)(b2 + n0);
            float4 v;
            v.x = acc2[mf][nf][0] + bb.x;
            v.y = acc2[mf][nf][1] + bb.y;
            v.z = acc2[mf][nf][2] + bb.z;
            v.w = acc2[mf][nf][3] + bb.w;
            *(float4*)(Out + (size_t)row * HDIM + n0) = v;
        }
    }
}

// ============================= fragment statistics =============================

__device__ __forceinline__ float blockReduceSum(float v, float* red) {
    #pragma unroll
    for (int off = 32; off > 0; off >>= 1)
        v += __shfl_down(v, off, 64);
    __syncthreads();
    if ((threadIdx.x & 63) == 0) red[threadIdx.x >> 6] = v;
    __syncthreads();
    return red[0] + red[1] + red[2] + red[3];
}

__device__ __forceinline__ float dot4(float4 a, float4 b) {
    return a.x * b.x + a.y * b.y + a.z * b.z + a.w * b.w;
}

__device__ void compute_invn_g(const float* __restrict__ Mat, int mult, int doff,
                               int c, int basep, const int* __restrict__ sorted,
                               float* invn, int tid)
{
    for (int p = tid; p < c; p += 256) {
        int nd = sorted[basep + p];
        const float4* row = (const float4*)(Mat + ((size_t)nd * mult + doff) * HDIM);
        float ss = 0.f;
        #pragma unroll 8
        for (int k = 0; k < 64; ++k) {
            float4 v = row[k];
            ss += v.x * v.x + v.y * v.y + v.z * v.z + v.w * v.w;
        }
        invn[p] = 1.0f / fmaxf(sqrtf(ss), 1e-12f);
    }
}

__device__ float pair_err_slow(const float* __restrict__ Mat, int mult, int doff,
                               int c, int basep, const int* __restrict__ sorted,
                               const float* invn, int tid)
{
    float e = 0.f;
    for (long pi = tid; pi < (long)c * c; pi += 256) {
        int i = (int)(pi / c), j = (int)(pi - (long)i * c);
        if (j <= i) continue;
        const float4* ri = (const float4*)(Mat + ((size_t)sorted[basep + i] * mult + doff) * HDIM);
        const float4* rj = (const float4*)(Mat + ((size_t)sorted[basep + j] * mult + doff) * HDIM);
        float dt = 0.f;
        for (int k = 0; k < 64; ++k) dt += dot4(ri[k], rj[k]);
        float sv = dt * invn[i] * invn[j];
        float d = sv - CSIM;
        e += d * d;
    }
    return e;
}

// One block per (fragment f, matrix m): m=0 -> SI, m=1..3 -> VI dim m-1.
__global__ __launch_bounds__(256)
void fragmat_kernel(const float* __restrict__ SI, const float* __restrict__ VI,
                    const int* __restrict__ counts, const int* __restrict__ offs,
                    const int* __restrict__ sorted, float* acc, float* nrm_global)
{
    const int f = blockIdx.x, m = blockIdx.y, tid = threadIdx.x;
    const int c = counts[f];
    if (c < 2) return;                      // invalid fragment: no contribution
    const int basep = offs[f];
    const float* Mat = (m == 0) ? SI : VI;
    const int mult = (m == 0) ? 1 : 3;
    const int doff = (m == 0) ? 0 : (m - 1);

    __shared__ __align__(16) float Z[CMAX * 260];   // 65 KB
    __shared__ float invn_s[CMAX];
    __shared__ float red[4];

    float var, err;

    if (c <= CMAX) {
        for (int u = tid; u < c * 64; u += 256) {
            int r = u >> 6, kc = u & 63;
            float4 v = *((const float4*)(Mat + ((size_t)sorted[basep + r] * mult + doff) * HDIM) + kc);
            *(float4*)&Z[r * 260 + (kc << 2)] = v;
        }
        __syncthreads();

        float msum = 0.f;
        for (int p = 0; p < c; ++p) msum += Z[p * 260 + tid];
        float mean = msum / (float)c;
        float vh = 0.f;
        for (int p = 0; p < c; ++p) {
            float d = Z[p * 260 + tid] - mean;
            vh += d * d;
        }
        var = blockReduceSum(vh, red);

        for (int p = tid; p < c; p += 256) {
            const float4* row = (const float4*)&Z[p * 260];
            float ss = 0.f;
            #pragma unroll 8
            for (int k = 0; k < 64; ++k) {
                float4 v = row[k];
                ss += v.x * v.x + v.y * v.y + v.z * v.z + v.w * v.w;
            }
            invn_s[p] = 1.0f / fmaxf(sqrtf(ss), 1e-12f);
        }
        __syncthreads();

        const int nb2 = (c + 1) >> 1;
        const int nbp = nb2 * (nb2 + 1) / 2;
        float e = 0.f;
        for (int u = tid; u < nbp; u += 256) {
            int bi = 0, rem = u;
            while (rem >= nb2 - bi) { rem -= nb2 - bi; ++bi; }
            int bj = bi + rem;
            int i0 = bi << 1, j0 = bj << 1;
            const float* zi0 = &Z[i0 * 260];
            const float* zi1 = &Z[(i0 + 1) * 260];
            const float* zj0 = &Z[j0 * 260];
            const float* zj1 = &Z[(j0 + 1) * 260];
            float s00 = 0.f, s01 = 0.f, s10 = 0.f, s11 = 0.f;
            #pragma unroll 4
            for (int k = 0; k < 64; ++k) {
                float4 a0 = *(const float4*)(zi0 + (k << 2));
                float4 a1 = *(const float4*)(zi1 + (k << 2));
                float4 b0 = *(const float4*)(zj0 + (k << 2));
                float4 b1 = *(const float4*)(zj1 + (k << 2));
                s00 += dot4(a0, b0);
                s01 += dot4(a0, b1);
                s10 += dot4(a1, b0);
                s11 += dot4(a1, b1);
            }
            int i1 = i0 + 1, j1 = j0 + 1;
            if (j0 > i0 && j0 < c) { float sv = s00 * invn_s[i0] * invn_s[j0] - CSIM; e += sv * sv; }
            if (j1 > i0 && j1 < c) { float sv = s01 * invn_s[i0] * invn_s[j1] - CSIM; e += sv * sv; }
            if (j0 > i1 && j0 < c) { float sv = s10 * invn_s[i1] * invn_s[j0] - CSIM; e += sv * sv; }
            if (j1 > i1 && j1 < c) { float sv = s11 * invn_s[i1] * invn_s[j1] - CSIM; e += sv * sv; }
        }
        err = blockReduceSum(e, red);
    } else {
        float msum = 0.f;
        for (int p = 0; p < c; ++p)
            msum += Mat[((size_t)sorted[basep + p] * mult + doff) * HDIM + tid];
        float mean = msum / (float)c;
        float vh = 0.f;
        for (int p = 0; p < c; ++p) {
            float d = Mat[((size_t)sorted[basep + p] * mult + doff) * HDIM + tid] - mean;
            vh += d * d;
        }
        var = blockReduceSum(vh, red);

        float* invn = nrm_global + (size_t)m * N_NODES + basep;
        compute_invn_g(Mat, mult, doff, c, basep, sorted, invn, tid);
        __syncthreads();
        float e = pair_err_slow(Mat, mult, doff, c, basep, sorted, invn, tid);
        err = blockReduceSum(e, red);
    }

    if (tid == 0) {
        float n = (float)c;
        float pc = 0.5f * n * (n - 1.f);
        float w_err = (m == 0) ? (0.5f / pc) : (0.5f / (3.f * pc));
        float contrib = 0.5f * var / n + err * w_err;
        atomicAdd(&acc[0], contrib);
        if (m == 0) atomicAdd(&acc[1], 1.0f);
    }
}

__global__ void finalize_kernel(const float* __restrict__ acc, float* __restrict__ out) {
    if (threadIdx.x == 0)
        out[0] = (acc[1] > 0.f) ? acc[0] / acc[1] : 0.f;
}

// ============================= launch =============================

extern "C" void kernel_launch(void* const* d_in, const int* in_sizes, int n_in,
                              void* d_out, int out_size, void* d_ws, size_t ws_size,
                              hipStream_t stream) {
    const float* s_short = (const float*)d_in[0];
    const float* s_long  = (const float*)d_in[1];
    const float* v_short = (const float*)d_in[2];
    const float* v_long  = (const float*)d_in[3];
    const float* W1 = (const float*)d_in[4];
    const float* b1 = (const float*)d_in[5];
    const float* W2 = (const float*)d_in[6];
    const float* b2 = (const float*)d_in[7];
    const float* V1 = (const float*)d_in[8];
    const float* V2 = (const float*)d_in[9];
    const int* fragRaw = (const int*)d_in[10];
    float* out = (float*)d_out;

    char* ws = (char*)d_ws;
    float*    SI     = (float*)(ws + SI_OFF);
    float*    VI     = (float*)(ws + VI_OFF);
    ushort_t* WH     = (ushort_t*)(ws + WH_OFF);
    ushort_t* WL     = (ushort_t*)(ws + WL_OFF);
    int*      counts = (int*)(ws + CNT_OFF);
    int*      cursor = (int*)(ws + CUR_OFF);
    int*      offs   = (int*)(ws + OFF_OFF);
    int*      sorted = (int*)(ws + SORT_OFF);
    float*    acc    = (float*)(ws + ACC_OFF);
    int*      flag   = (int*)(ws + FLG_OFF);
    float*    nrm    = (float*)(ws + NRM_OFF);
    int*      fragN  = (int*)(ws + FRGN_OFF);

    init_kernel<<<1, 256, 0, stream>>>(counts, cursor, acc, flag);
    detect_kernel<<<16, 256, 0, stream>>>(fragRaw, flag);
    normalize_kernel<<<N_NODES / 256, 256, 0, stream>>>(fragRaw, flag, fragN);
    hist_kernel<<<N_NODES / 256, 256, 0, stream>>>(fragN, counts);
    scan_kernel<<<1, 256, 0, stream>>>(counts, offs);
    scatter_kernel<<<N_NODES / 256, 256, 0, stream>>>(fragN, offs, cursor, sorted);
    wsplit_kernel<<<dim3(256, 4), 256, 0, stream>>>(W1, W2, V1, V2, WH, WL);

    // scalar branch: SI = ssp(mix@W1+b1)@W2+b2  (fused, 256 blocks)
    mlp_fused<true, true><<<dim3(N_NODES / 32), 256, 0, stream>>>(
        s_short, s_long, WH + 0 * 65536, WL + 0 * 65536,
        WH + 1 * 65536, WL + 1 * 65536, b1, b2, SI);
    // vector branch: VI = ssp(mix@V1)@V2  (fused, 768 blocks)
    mlp_fused<false, false><<<dim3(3 * N_NODES / 32), 256, 0, stream>>>(
        v_short, v_long, WH + 2 * 65536, WL + 2 * 65536,
        WH + 3 * 65536, WL + 3 * 65536, nullptr, nullptr, VI);

    fragmat_kernel<<<dim3(NFRAG, 4), 256, 0, stream>>>(SI, VI, counts, offs, sorted, acc, nrm);
    finalize_kernel<<<1, 64, 0, stream>>>(acc, out);
}

// Round 10
// 209.484 us; speedup vs baseline: 3.1466x; 1.2179x over previous
//
#include <hip/hip_runtime.h>
#include <cmath>

#define N_NODES 8192
#define HDIM 256
#define NFRAG 256
#define RMIX 0.3f
#define CSIM 0.8f
#define LN2 0.6931471805599453f
#define CMAX 64          // LDS fast-path row capacity per (fragment, matrix)

typedef __bf16 bf16x8 __attribute__((ext_vector_type(8)));
typedef float f32x4 __attribute__((ext_vector_type(4)));
typedef unsigned short us8 __attribute__((ext_vector_type(8)));
typedef unsigned short us4 __attribute__((ext_vector_type(4)));
typedef unsigned short ushort_t;

// ---- workspace layout (bytes) ----
#define SI_OFF   ((size_t)0)                    // 8192*256*4  = 8 MB
#define VI_OFF   ((size_t)8388608)              // 24576*256*4 = 24 MB
#define WH_OFF   ((size_t)58720256)             // 4 * 65536 * 2 = 524,288
#define WL_OFF   ((size_t)59244544)             // 524,288
#define CNT_OFF  ((size_t)59768832)             // 256 ints
#define CUR_OFF  (CNT_OFF + 1024)
#define OFF_OFF  (CNT_OFF + 2048)
#define SORT_OFF (CNT_OFF + 3072)               // 8192 ints
#define ACC_OFF  (SORT_OFF + 32768)
#define FLG_OFF  (ACC_OFF + 128)
#define NRM_OFF  (ACC_OFF + 256)                // 4 regions x 8192 floats
#define FRGN_OFF (NRM_OFF + 4 * 32768)          // 8192 ints

// ---- bf16 split helpers (RNE) ----
__device__ __forceinline__ ushort_t f2bf(float x) {
    unsigned u = __float_as_uint(x);
    return (ushort_t)((u + 0x7FFFu + ((u >> 16) & 1u)) >> 16);
}
__device__ __forceinline__ float bf2f(ushort_t h) {
    return __uint_as_float(((unsigned)h) << 16);
}
__device__ __forceinline__ f32x4 mfma_bf16(us8 a, us8 b, f32x4 c) {
    return __builtin_amdgcn_mfma_f32_16x16x32_bf16(
        __builtin_bit_cast(bf16x8, a), __builtin_bit_cast(bf16x8, b), c, 0, 0, 0);
}

// ============================= setup kernels =============================

__global__ void init_kernel(int* counts, int* cursor, float* acc, int* flag) {
    int t = threadIdx.x;
    if (t < NFRAG) { counts[t] = 0; cursor[t] = 0; }
    if (t < 8) acc[t] = 0.f;
    if (t == 0) *flag = 0;
}

// fragment_ids may arrive as raw int64 (reference dtype) or converted int32.
// int64 LE -> int32 view is [id,0,id,0,...]: odd positions all zero (ids<256).
__global__ void detect_kernel(const int* __restrict__ buf, int* flag) {
    int i = blockIdx.x * 256 + threadIdx.x;       // 0..4095
    if (buf[2 * i + 1] != 0) atomicOr(flag, 1);   // 1 => plain int32 layout
}

__global__ void normalize_kernel(const int* __restrict__ buf, const int* __restrict__ flag,
                                 int* __restrict__ fragN) {
    int i = blockIdx.x * 256 + threadIdx.x;
    if (i < N_NODES) fragN[i] = (*flag) ? buf[i] : buf[2 * i];
}

__global__ void hist_kernel(const int* __restrict__ frag, int* counts) {
    int i = blockIdx.x * 256 + threadIdx.x;
    if (i < N_NODES) atomicAdd(&counts[frag[i]], 1);
}

__global__ void scan_kernel(const int* __restrict__ counts, int* offs) {
    __shared__ int tmp[NFRAG];
    int t = threadIdx.x;
    tmp[t] = counts[t];
    __syncthreads();
    for (int off = 1; off < NFRAG; off <<= 1) {
        int v = (t >= off) ? tmp[t - off] : 0;
        __syncthreads();
        tmp[t] += v;
        __syncthreads();
    }
    offs[t] = tmp[t] - counts[t];   // exclusive scan
}

__global__ void scatter_kernel(const int* __restrict__ frag, const int* __restrict__ offs,
                               int* cursor, int* sorted) {
    int i = blockIdx.x * 256 + threadIdx.x;
    if (i < N_NODES) {
        int f = frag[i];
        int pos = offs[f] + atomicAdd(&cursor[f], 1);
        sorted[pos] = i;
    }
}

// Split the 4 weight matrices into bf16 hi/lo in MFMA-fragment-native layout:
// dst[((kb*256 + n)*4 + kg)*8 + e] = W[(kb*32 + kg*8 + e)*256 + n]
__global__ void wsplit_kernel(const float* __restrict__ W1, const float* __restrict__ W2,
                              const float* __restrict__ V1, const float* __restrict__ V2,
                              ushort_t* __restrict__ Whi, ushort_t* __restrict__ Wlo) {
    int m = blockIdx.y;
    const float* src = (m == 0) ? W1 : (m == 1) ? W2 : (m == 2) ? V1 : V2;
    ushort_t* dh = Whi + m * 65536;
    ushort_t* dl = Wlo + m * 65536;
    int o = blockIdx.x * 256 + threadIdx.x;   // 0..65535
    int e = o & 7, kg = (o >> 3) & 3, n = (o >> 5) & 255, kb = o >> 13;
    float x = src[(size_t)(kb * 32 + kg * 8 + e) * HDIM + n];
    ushort_t h = f2bf(x);
    dh[o] = h;
    dl[o] = f2bf(x - bf2f(h));
}

// ============================= fused 2-layer MLP, merged branches =============================
// One dispatch for scalar (rows [0,8192)) and vector (rows [8192,32768)).
// Block = 256 thr (4 waves), BM=64 rows, BN=256 full width; split-bf16 4-pass.
// LDS 64 KB: 64x256 bf16 hi/lo activation tile, XOR-swizzled, reused A->T.
// Swapped mfma operands (verified on HW, rounds 7/9 absmax 0.0): lane holds
// output row m=lr (per mf frag) and 4 consecutive cols n0 = colW+nf*16+kg*4.
// Grid 512 blocks = exactly 2 blocks/CU; W panels (512 KB/branch) stay L2-hot
// and are re-read by half as many blocks as round 9.

__global__ __launch_bounds__(256)
void mlp_fused_all(const float* __restrict__ s_short, const float* __restrict__ s_long,
                   const float* __restrict__ v_short, const float* __restrict__ v_long,
                   const ushort_t* __restrict__ WH, const ushort_t* __restrict__ WL,
                   const float* __restrict__ b1, const float* __restrict__ b2,
                   float* __restrict__ SI, float* __restrict__ VI)
{
    __shared__ __align__(16) ushort_t Zh[64 * 256];   // 32 KB
    __shared__ __align__(16) ushort_t Zl[64 * 256];   // 32 KB

    const int tid = threadIdx.x;
    const int l   = tid & 63;
    const int wid = tid >> 6;
    const int lr  = l & 15;
    const int kg  = l >> 4;
    const int colW = wid * 64;

    const int rowBase = blockIdx.x * 64;
    const bool isScalar = (rowBase < N_NODES);
    const float* A0;
    const float* A1;
    float* Out;
    const ushort_t *B1h, *B1l, *B2h, *B2l;
    if (isScalar) {
        size_t off = (size_t)rowBase * HDIM;
        A0 = s_short + off;  A1 = s_long + off;  Out = SI + off;
        B1h = WH;              B1l = WL;
        B2h = WH + 65536;      B2l = WL + 65536;
    } else {
        size_t off = (size_t)(rowBase - N_NODES) * HDIM;
        A0 = v_short + off;  A1 = v_long + off;  Out = VI + off;
        B1h = WH + 2 * 65536;  B1l = WL + 2 * 65536;
        B2h = WH + 3 * 65536;  B2l = WL + 3 * 65536;
    }

    // ---- phase 0: coalesced load + mix + split -> LDS (64 elems/thread) ----
    {
        int r  = tid >> 2;               // 0..63 local row
        int c0 = (tid & 3) * 64;         // 64-float run
        const float* ps = A0 + (size_t)r * HDIM + c0;
        const float* pl = A1 + (size_t)r * HDIM + c0;
        int swz = (r & 7) << 3;
        #pragma unroll
        for (int cc = 0; cc < 8; ++cc) {
            float4 s0 = *(const float4*)(ps + cc * 8);
            float4 s1 = *(const float4*)(ps + cc * 8 + 4);
            float4 t0 = *(const float4*)(pl + cc * 8);
            float4 t1 = *(const float4*)(pl + cc * 8 + 4);
            float x[8];
            x[0] = s0.x * RMIX + t0.x * (1.f - RMIX);
            x[1] = s0.y * RMIX + t0.y * (1.f - RMIX);
            x[2] = s0.z * RMIX + t0.z * (1.f - RMIX);
            x[3] = s0.w * RMIX + t0.w * (1.f - RMIX);
            x[4] = s1.x * RMIX + t1.x * (1.f - RMIX);
            x[5] = s1.y * RMIX + t1.y * (1.f - RMIX);
            x[6] = s1.z * RMIX + t1.z * (1.f - RMIX);
            x[7] = s1.w * RMIX + t1.w * (1.f - RMIX);
            us8 h, lo;
            #pragma unroll
            for (int e = 0; e < 8; ++e) {
                ushort_t hh = f2bf(x[e]);
                h[e] = hh;
                lo[e] = f2bf(x[e] - bf2f(hh));
            }
            int idx = r * 256 + ((c0 + cc * 8) ^ swz);
            *(us8*)&Zh[idx] = h;
            *(us8*)&Zl[idx] = lo;
        }
    }
    __syncthreads();

    // lane-level W base: offset = (colW+lr)*32 + kg*8; +nf*512 imm; +kb*8192 step
    const int wbase = (colW + lr) * 32 + kg * 8;

    // ---- phase 1: acc = mix @ W1 ----
    f32x4 acc[4][4];
    #pragma unroll
    for (int mf = 0; mf < 4; ++mf)
        #pragma unroll
        for (int nf = 0; nf < 4; ++nf)
            acc[mf][nf] = f32x4{0.f, 0.f, 0.f, 0.f};

    {
        const ushort_t* ph = B1h + wbase;
        const ushort_t* pl = B1l + wbase;
        for (int kb = 0; kb < 8; ++kb) {
            const int kx = kb * 32 + kg * 8;
            us8 ah[4], al[4];
            #pragma unroll
            for (int mf = 0; mf < 4; ++mf) {
                int m = mf * 16 + lr;
                int idx = m * 256 + (kx ^ ((m & 7) << 3));
                ah[mf] = *(const us8*)&Zh[idx];
                al[mf] = *(const us8*)&Zl[idx];
            }
            #pragma unroll
            for (int nf = 0; nf < 4; ++nf) {
                us8 wh = *(const us8*)(ph + nf * 512);
                us8 wl = *(const us8*)(pl + nf * 512);
                #pragma unroll
                for (int mf = 0; mf < 4; ++mf) {
                    f32x4 t = acc[mf][nf];
                    t = mfma_bf16(wl, al[mf], t);
                    t = mfma_bf16(wl, ah[mf], t);
                    t = mfma_bf16(wh, al[mf], t);
                    t = mfma_bf16(wh, ah[mf], t);
                    acc[mf][nf] = t;
                }
            }
            ph += 8192; pl += 8192;
        }
    }
    __syncthreads();   // all waves done reading A tile

    // ---- layer-1 epilogue: bias + SSP, split, T -> LDS (overwrites A) ----
    #pragma unroll
    for (int mf = 0; mf < 4; ++mf) {
        int m = mf * 16 + lr;
        #pragma unroll
        for (int nf = 0; nf < 4; ++nf) {
            int n0 = colW + nf * 16 + kg * 4;
            float4 bb = {0.f, 0.f, 0.f, 0.f};
            if (isScalar) bb = *(const float4*)(b1 + n0);
            us4 h4, l4;
            #pragma unroll
            for (int r = 0; r < 4; ++r) {
                float x = acc[mf][nf][r] + ((const float*)&bb)[r];
                // ssp: max(x,0)+log1p(exp(-|x|))-ln2; __logf form: T's split-bf16
                // representation error (~2^-17 rel) dominates the ~1e-7 approx err.
                x = fmaxf(x, 0.f) + __logf(1.f + __expf(-fabsf(x))) - LN2;
                ushort_t hh = f2bf(x);
                h4[r] = hh;
                l4[r] = f2bf(x - bf2f(hh));
            }
            int idx = m * 256 + (n0 ^ ((m & 7) << 3));
            *(us4*)&Zh[idx] = h4;
            *(us4*)&Zl[idx] = l4;
        }
    }
    __syncthreads();

    // ---- phase 2: acc2 = T @ W2 ----
    f32x4 acc2[4][4];
    #pragma unroll
    for (int mf = 0; mf < 4; ++mf)
        #pragma unroll
        for (int nf = 0; nf < 4; ++nf)
            acc2[mf][nf] = f32x4{0.f, 0.f, 0.f, 0.f};

    {
        const ushort_t* ph = B2h + wbase;
        const ushort_t* pl = B2l + wbase;
        for (int kb = 0; kb < 8; ++kb) {
            const int kx = kb * 32 + kg * 8;
            us8 ah[4], al[4];
            #pragma unroll
            for (int mf = 0; mf < 4; ++mf) {
                int m = mf * 16 + lr;
                int idx = m * 256 + (kx ^ ((m & 7) << 3));
                ah[mf] = *(const us8*)&Zh[idx];
                al[mf] = *(const us8*)&Zl[idx];
            }
            #pragma unroll
            for (int nf = 0; nf < 4; ++nf) {
                us8 wh = *(const us8*)(ph + nf * 512);
                us8 wl = *(const us8*)(pl + nf * 512);
                #pragma unroll
                for (int mf = 0; mf < 4; ++mf) {
                    f32x4 t = acc2[mf][nf];
                    t = mfma_bf16(wl, al[mf], t);
                    t = mfma_bf16(wl, ah[mf], t);
                    t = mfma_bf16(wh, al[mf], t);
                    t = mfma_bf16(wh, ah[mf], t);
                    acc2[mf][nf] = t;
                }
            }
            ph += 8192; pl += 8192;
        }
    }

    // ---- final epilogue: bias2 (scalar branch), float4 store ----
    #pragma unroll
    for (int mf = 0; mf < 4; ++mf) {
        int m = mf * 16 + lr;
        #pragma unroll
        for (int nf = 0; nf < 4; ++nf) {
            int n0 = colW + nf * 16 + kg * 4;
            float4 bb = {0.f, 0.f, 0.f, 0.f};
            if (isScalar) bb = *(const float4*)(b2 + n0);
            float4 v;
            v.x = acc2[mf][nf][0] + bb.x;
            v.y = acc2[mf][nf][1] + bb.y;
            v.z = acc2[mf][nf][2] + bb.z;
            v.w = acc2[mf][nf][3] + bb.w;
            *(float4*)(Out + (size_t)m * HDIM + n0) = v;
        }
    }
}

// ============================= fragment statistics =============================

__device__ __forceinline__ float blockReduceSum(float v, float* red) {
    #pragma unroll
    for (int off = 32; off > 0; off >>= 1)
        v += __shfl_down(v, off, 64);
    __syncthreads();
    if ((threadIdx.x & 63) == 0) red[threadIdx.x >> 6] = v;
    __syncthreads();
    return red[0] + red[1] + red[2] + red[3];
}

__device__ __forceinline__ float dot4(float4 a, float4 b) {
    return a.x * b.x + a.y * b.y + a.z * b.z + a.w * b.w;
}

__device__ void compute_invn_g(const float* __restrict__ Mat, int mult, int doff,
                               int c, int basep, const int* __restrict__ sorted,
                               float* invn, int tid)
{
    for (int p = tid; p < c; p += 256) {
        int nd = sorted[basep + p];
        const float4* row = (const float4*)(Mat + ((size_t)nd * mult + doff) * HDIM);
        float ss = 0.f;
        #pragma unroll 8
        for (int k = 0; k < 64; ++k) {
            float4 v = row[k];
            ss += v.x * v.x + v.y * v.y + v.z * v.z + v.w * v.w;
        }
        invn[p] = 1.0f / fmaxf(sqrtf(ss), 1e-12f);
    }
}

__device__ float pair_err_slow(const float* __restrict__ Mat, int mult, int doff,
                               int c, int basep, const int* __restrict__ sorted,
                               const float* invn, int tid)
{
    float e = 0.f;
    for (long pi = tid; pi < (long)c * c; pi += 256) {
        int i = (int)(pi / c), j = (int)(pi - (long)i * c);
        if (j <= i) continue;
        const float4* ri = (const float4*)(Mat + ((size_t)sorted[basep + i] * mult + doff) * HDIM);
        const float4* rj = (const float4*)(Mat + ((size_t)sorted[basep + j] * mult + doff) * HDIM);
        float dt = 0.f;
        for (int k = 0; k < 64; ++k) dt += dot4(ri[k], rj[k]);
        float sv = dt * invn[i] * invn[j];
        float d = sv - CSIM;
        e += d * d;
    }
    return e;
}

// One block per (fragment f, matrix m): m=0 -> SI, m=1..3 -> VI dim m-1.
__global__ __launch_bounds__(256)
void fragmat_kernel(const float* __restrict__ SI, const float* __restrict__ VI,
                    const int* __restrict__ counts, const int* __restrict__ offs,
                    const int* __restrict__ sorted, float* acc, float* nrm_global)
{
    const int f = blockIdx.x, m = blockIdx.y, tid = threadIdx.x;
    const int c = counts[f];
    if (c < 2) return;                      // invalid fragment: no contribution
    const int basep = offs[f];
    const float* Mat = (m == 0) ? SI : VI;
    const int mult = (m == 0) ? 1 : 3;
    const int doff = (m == 0) ? 0 : (m - 1);

    __shared__ __align__(16) float Z[CMAX * 260];   // 65 KB
    __shared__ float invn_s[CMAX];
    __shared__ float red[4];

    float var, err;

    if (c <= CMAX) {
        for (int u = tid; u < c * 64; u += 256) {
            int r = u >> 6, kc = u & 63;
            float4 v = *((const float4*)(Mat + ((size_t)sorted[basep + r] * mult + doff) * HDIM) + kc);
            *(float4*)&Z[r * 260 + (kc << 2)] = v;
        }
        __syncthreads();

        float msum = 0.f;
        for (int p = 0; p < c; ++p) msum += Z[p * 260 + tid];
        float mean = msum / (float)c;
        float vh = 0.f;
        for (int p = 0; p < c; ++p) {
            float d = Z[p * 260 + tid] - mean;
            vh += d * d;
        }
        var = blockReduceSum(vh, red);

        for (int p = tid; p < c; p += 256) {
            const float4* row = (const float4*)&Z[p * 260];
            float ss = 0.f;
            #pragma unroll 8
            for (int k = 0; k < 64; ++k) {
                float4 v = row[k];
                ss += v.x * v.x + v.y * v.y + v.z * v.z + v.w * v.w;
            }
            invn_s[p] = 1.0f / fmaxf(sqrtf(ss), 1e-12f);
        }
        __syncthreads();

        const int nb2 = (c + 1) >> 1;
        const int nbp = nb2 * (nb2 + 1) / 2;
        float e = 0.f;
        for (int u = tid; u < nbp; u += 256) {
            int bi = 0, rem = u;
            while (rem >= nb2 - bi) { rem -= nb2 - bi; ++bi; }
            int bj = bi + rem;
            int i0 = bi << 1, j0 = bj << 1;
            const float* zi0 = &Z[i0 * 260];
            const float* zi1 = &Z[(i0 + 1) * 260];
            const float* zj0 = &Z[j0 * 260];
            const float* zj1 = &Z[(j0 + 1) * 260];
            float s00 = 0.f, s01 = 0.f, s10 = 0.f, s11 = 0.f;
            #pragma unroll 4
            for (int k = 0; k < 64; ++k) {
                float4 a0 = *(const float4*)(zi0 + (k << 2));
                float4 a1 = *(const float4*)(zi1 + (k << 2));
                float4 b0 = *(const float4*)(zj0 + (k << 2));
                float4 b1 = *(const float4*)(zj1 + (k << 2));
                s00 += dot4(a0, b0);
                s01 += dot4(a0, b1);
                s10 += dot4(a1, b0);
                s11 += dot4(a1, b1);
            }
            int i1 = i0 + 1, j1 = j0 + 1;
            if (j0 > i0 && j0 < c) { float sv = s00 * invn_s[i0] * invn_s[j0] - CSIM; e += sv * sv; }
            if (j1 > i0 && j1 < c) { float sv = s01 * invn_s[i0] * invn_s[j1] - CSIM; e += sv * sv; }
            if (j0 > i1 && j0 < c) { float sv = s10 * invn_s[i1] * invn_s[j0] - CSIM; e += sv * sv; }
            if (j1 > i1 && j1 < c) { float sv = s11 * invn_s[i1] * invn_s[j1] - CSIM; e += sv * sv; }
        }
        err = blockReduceSum(e, red);
    } else {
        float msum = 0.f;
        for (int p = 0; p < c; ++p)
            msum += Mat[((size_t)sorted[basep + p] * mult + doff) * HDIM + tid];
        float mean = msum / (float)c;
        float vh = 0.f;
        for (int p = 0; p < c; ++p) {
            float d = Mat[((size_t)sorted[basep + p] * mult + doff) * HDIM + tid] - mean;
            vh += d * d;
        }
        var = blockReduceSum(vh, red);

        float* invn = nrm_global + (size_t)m * N_NODES + basep;
        compute_invn_g(Mat, mult, doff, c, basep, sorted, invn, tid);
        __syncthreads();
        float e = pair_err_slow(Mat, mult, doff, c, basep, sorted, invn, tid);
        err = blockReduceSum(e, red);
    }

    if (tid == 0) {
        float n = (float)c;
        float pc = 0.5f * n * (n - 1.f);
        float w_err = (m == 0) ? (0.5f / pc) : (0.5f / (3.f * pc));
        float contrib = 0.5f * var / n + err * w_err;
        atomicAdd(&acc[0], contrib);
        if (m == 0) atomicAdd(&acc[1], 1.0f);
    }
}

__global__ void finalize_kernel(const float* __restrict__ acc, float* __restrict__ out) {
    if (threadIdx.x == 0)
        out[0] = (acc[1] > 0.f) ? acc[0] / acc[1] : 0.f;
}

// ============================= launch =============================

extern "C" void kernel_launch(void* const* d_in, const int* in_sizes, int n_in,
                              void* d_out, int out_size, void* d_ws, size_t ws_size,
                              hipStream_t stream) {
    const float* s_short = (const float*)d_in[0];
    const float* s_long  = (const float*)d_in[1];
    const float* v_short = (const float*)d_in[2];
    const float* v_long  = (const float*)d_in[3];
    const float* W1 = (const float*)d_in[4];
    const float* b1 = (const float*)d_in[5];
    const float* W2 = (const float*)d_in[6];
    const float* b2 = (const float*)d_in[7];
    const float* V1 = (const float*)d_in[8];
    const float* V2 = (const float*)d_in[9];
    const int* fragRaw = (const int*)d_in[10];
    float* out = (float*)d_out;

    char* ws = (char*)d_ws;
    float*    SI     = (float*)(ws + SI_OFF);
    float*    VI     = (float*)(ws + VI_OFF);
    ushort_t* WH     = (ushort_t*)(ws + WH_OFF);
    ushort_t* WL     = (ushort_t*)(ws + WL_OFF);
    int*      counts = (int*)(ws + CNT_OFF);
    int*      cursor = (int*)(ws + CUR_OFF);
    int*      offs   = (int*)(ws + OFF_OFF);
    int*      sorted = (int*)(ws + SORT_OFF);
    float*    acc    = (float*)(ws + ACC_OFF);
    int*      flag   = (int*)(ws + FLG_OFF);
    float*    nrm    = (float*)(ws + NRM_OFF);
    int*      fragN  = (int*)(ws + FRGN_OFF);

    init_kernel<<<1, 256, 0, stream>>>(counts, cursor, acc, flag);
    detect_kernel<<<16, 256, 0, stream>>>(fragRaw, flag);
    normalize_kernel<<<N_NODES / 256, 256, 0, stream>>>(fragRaw, flag, fragN);
    hist_kernel<<<N_NODES / 256, 256, 0, stream>>>(fragN, counts);
    scan_kernel<<<1, 256, 0, stream>>>(counts, offs);
    scatter_kernel<<<N_NODES / 256, 256, 0, stream>>>(fragN, offs, cursor, sorted);
    wsplit_kernel<<<dim3(256, 4), 256, 0, stream>>>(W1, W2, V1, V2, WH, WL);

    // both MLP branches in one dispatch: 512 blocks of 64 rows (2 blocks/CU)
    mlp_fused_all<<<dim3((N_NODES + 3 * N_NODES) / 64), 256, 0, stream>>>(
        s_short, s_long, v_short, v_long, WH, WL, b1, b2, SI, VI);

    fragmat_kernel<<<dim3(NFRAG, 4), 256, 0, stream>>>(SI, VI, counts, offs, sorted, acc, nrm);
    finalize_kernel<<<1, 64, 0, stream>>>(acc, out);
}